// Round 5
// baseline (12122.990 us; speedup 1.0000x reference)
//
#include <hip/hip_runtime.h>
#include <math.h>

#define B 2048
#define H 256
#define INDIM 320
#define NOPS 1883
#define STEPS 20
#define GRIDN 512

typedef _Float16 f16;
typedef _Float16 f16x4 __attribute__((ext_vector_type(4)));
typedef _Float16 f16x8 __attribute__((ext_vector_type(8)));
typedef float f32x4 __attribute__((ext_vector_type(4)));
typedef unsigned long long u64;

// XOR swizzle: 4 16B-slots per 64B row; bijective involution per row.
#define SWZ(r, s) ((s) ^ ((r) & 3) ^ (((r) >> 2) & 1))

#define S1 (1.0f / 1024.0f)
#define S2 (1.0f / 1048576.0f)

__device__ __forceinline__ void split3(float f, f16& c0, f16& c1, f16& c2) {
    c0 = (f16)f;
    float r1 = f - (float)c0;
    c1 = (f16)(r1 * 1024.0f);
    float r2 = r1 - (float)c1 * S1;
    c2 = (f16)(r2 * 1048576.0f);
}

// ---------------- device-scope grid barrier (all GRIDN blocks co-resident) -----------
__device__ __forceinline__ void gridbar(unsigned* cnt, unsigned target) {
    __syncthreads();
    if (threadIdx.x == 0) {
        __threadfence();
        __hip_atomic_fetch_add(cnt, 1u, __ATOMIC_ACQ_REL, __HIP_MEMORY_SCOPE_AGENT);
        while (__hip_atomic_load(cnt, __ATOMIC_ACQUIRE, __HIP_MEMORY_SCOPE_AGENT) < target)
            __builtin_amdgcn_s_sleep(1);
        __threadfence();
    }
    __syncthreads();
}

// ---------------- init: x = concat(geo,sem) triple-split; zero h state + reductions ---
__global__ __launch_bounds__(256) void init_kernel(const float* __restrict__ geo,
                                                   const float* __restrict__ sem,
                                                   f16* __restrict__ x0, f16* __restrict__ x1,
                                                   f16* __restrict__ x2,
                                                   float* __restrict__ h0f, float* __restrict__ h1f,
                                                   f16* __restrict__ h0c0, f16* __restrict__ h0c1,
                                                   f16* __restrict__ h0c2,
                                                   f16* __restrict__ h1c0, f16* __restrict__ h1c1,
                                                   f16* __restrict__ h1c2,
                                                   float* __restrict__ hsq, u64* __restrict__ amax,
                                                   unsigned* __restrict__ cnt) {
    int i = blockIdx.x * blockDim.x + threadIdx.x;
    if (i == 0) *cnt = 0u;
    if (i < B * INDIM) {
        int b = i / INDIM, c = i % INDIM;
        float f = (c < 256) ? geo[b * 256 + c] : sem[b * 64 + (c - 256)];
        f16 a, bb, cc;
        split3(f, a, bb, cc);
        x0[i] = a; x1[i] = bb; x2[i] = cc;
    }
    if (i < B * H) {
        h0f[i] = 0.0f; h1f[i] = 0.0f;
        h0c0[i] = (f16)0.0f; h0c1[i] = (f16)0.0f; h0c2[i] = (f16)0.0f;
        h1c0[i] = (f16)0.0f; h1c1[i] = (f16)0.0f; h1c2[i] = (f16)0.0f;
    }
    if (i < B) { hsq[i] = 0.0f; amax[i] = 0ull; }
}

// ---------------- generic tiled GEMM (used only for opp precompute) ----------------
#define BM 64
#define BN 64
#define BK 16
__global__ __launch_bounds__(256) void gemm_tn(const float* __restrict__ A,
                                               const float* __restrict__ Bm,
                                               const float* __restrict__ bias,
                                               float* __restrict__ C,
                                               int M, int N, int K) {
    __shared__ float As[BK][BM];
    __shared__ float Bs[BK][BN];
    int tid = threadIdx.x;
    int bm0 = blockIdx.y * BM;
    int bn0 = blockIdx.x * BN;
    int tx = tid & 15, ty = tid >> 4;
    int lr = tid >> 2;
    int lk = (tid & 3) << 2;

    float acc[4][4];
#pragma unroll
    for (int i = 0; i < 4; ++i)
#pragma unroll
        for (int j = 0; j < 4; ++j) acc[i][j] = 0.0f;

    for (int k0 = 0; k0 < K; k0 += BK) {
        {
            int gr = bm0 + lr;
            float4 v = make_float4(0.f, 0.f, 0.f, 0.f);
            if (gr < M) v = *(const float4*)(A + (size_t)gr * K + k0 + lk);
            As[lk + 0][lr] = v.x; As[lk + 1][lr] = v.y;
            As[lk + 2][lr] = v.z; As[lk + 3][lr] = v.w;
        }
        {
            int gn = bn0 + lr;
            float4 v = make_float4(0.f, 0.f, 0.f, 0.f);
            if (gn < N) v = *(const float4*)(Bm + (size_t)gn * K + k0 + lk);
            Bs[lk + 0][lr] = v.x; Bs[lk + 1][lr] = v.y;
            Bs[lk + 2][lr] = v.z; Bs[lk + 3][lr] = v.w;
        }
        __syncthreads();
#pragma unroll
        for (int k = 0; k < BK; ++k) {
            float a[4], b[4];
#pragma unroll
            for (int i = 0; i < 4; ++i) a[i] = As[k][ty * 4 + i];
#pragma unroll
            for (int j = 0; j < 4; ++j) b[j] = Bs[k][tx * 4 + j];
#pragma unroll
            for (int i = 0; i < 4; ++i)
#pragma unroll
                for (int j = 0; j < 4; ++j) acc[i][j] = fmaf(a[i], b[j], acc[i][j]);
        }
        __syncthreads();
    }
#pragma unroll
    for (int i = 0; i < 4; ++i) {
        int gr = bm0 + ty * 4 + i;
        if (gr >= M) continue;
#pragma unroll
        for (int j = 0; j < 4; ++j) {
            int gc = bn0 + tx * 4 + j;
            if (gc < N) C[(size_t)gr * N + gc] = acc[i][j] + (bias ? bias[gc] : 0.0f);
        }
    }
}

// ---------------- fp32 -> fp16 hi/lo double split (lo x1024) + optional row sumsq -----
__global__ __launch_bounds__(256) void cvt_rows(const float* __restrict__ A, int rows, int cols,
                                                f16* __restrict__ hi, f16* __restrict__ lo,
                                                float* __restrict__ sq) {
    int row = blockIdx.x * 4 + (threadIdx.x >> 6);
    int lane = threadIdx.x & 63;
    if (row >= rows) return;
    const float* src = A + (size_t)row * cols;
    float s = 0.0f;
    for (int c0 = 0; c0 < cols; c0 += 256) {
        int idx = c0 + lane * 4;
        if (idx < cols) {
            float4 v = *(const float4*)(src + idx);
            float vv[4] = {v.x, v.y, v.z, v.w};
            f16x4 h, l;
#pragma unroll
            for (int j = 0; j < 4; ++j) {
                float f = vv[j];
                f16 hv = (f16)f;
                h[j] = hv;
                l[j] = (f16)((f - (float)hv) * 1024.0f);
                s = fmaf(f, f, s);
            }
            *(f16x4*)(hi + (size_t)row * cols + idx) = h;
            *(f16x4*)(lo + (size_t)row * cols + idx) = l;
        }
    }
    if (sq) {
#pragma unroll
        for (int off = 32; off > 0; off >>= 1) s += __shfl_down(s, off);
        if (lane == 0) sq[row] = s;
    }
}

// ---------------- fp32 -> fp16 triple split ----------------
__global__ __launch_bounds__(256) void cvt3_rows(const float* __restrict__ A, int rows, int cols,
                                                 f16* __restrict__ o0, f16* __restrict__ o1,
                                                 f16* __restrict__ o2) {
    int row = blockIdx.x * 4 + (threadIdx.x >> 6);
    int lane = threadIdx.x & 63;
    if (row >= rows) return;
    const float* src = A + (size_t)row * cols;
    for (int c0 = 0; c0 < cols; c0 += 256) {
        int idx = c0 + lane * 4;
        if (idx < cols) {
            float4 v = *(const float4*)(src + idx);
            float vv[4] = {v.x, v.y, v.z, v.w};
            f16x4 a, b, c;
#pragma unroll
            for (int j = 0; j < 4; ++j) {
                f16 p, q, r;
                split3(vv[j], p, q, r);
                a[j] = p; b[j] = q; c[j] = r;
            }
            *(f16x4*)(o0 + (size_t)row * cols + idx) = a;
            *(f16x4*)(o1 + (size_t)row * cols + idx) = b;
            *(f16x4*)(o2 + (size_t)row * cols + idx) = c;
        }
    }
}

// ---------------- triple-split MFMA GRU k-loop (device) ----------------
__device__ __forceinline__ void gru_phase3(
    const f16* __restrict__ A0, const f16* __restrict__ A1, const f16* __restrict__ A2,
    const f16* __restrict__ W0, const f16* __restrict__ W1, const f16* __restrict__ W2,
    int K, int m0, int c0, int tid, int lane, int mw, int hhalf,
    f32x4* acc, f32x4* accx, f32x4* accy, f16* sA, f16* sW) {
    for (int k0 = 0; k0 < K; k0 += 32) {
#pragma unroll
        for (int it = 0; it < 2; ++it) {
            int flat = tid + 256 * it;
            if (flat < 384) {
                int third = flat >> 7;
                int within = flat & 127;
                int row = within >> 2, slot = within & 3;
                const f16* src = (third == 0 ? A0 : third == 1 ? A1 : A2)
                                 + (size_t)(m0 + row) * K + k0 + slot * 8;
                *(float4*)&sA[third * 1024 + row * 32 + SWZ(row, slot) * 8] = *(const float4*)src;
            }
        }
#pragma unroll
        for (int third = 0; third < 3; ++third)
#pragma unroll
            for (int it = 0; it < 2; ++it) {
                int flat = tid + 256 * it;
                if (flat < 384) {
                    int row = flat >> 2, slot = flat & 3;
                    int wr = ((row >> 5) << 8) + c0 + (row & 31);
                    const f16* src = (third == 0 ? W0 : third == 1 ? W1 : W2)
                                     + (size_t)wr * K + k0 + slot * 8;
                    *(float4*)&sW[third * 3072 + row * 32 + SWZ(row, slot) * 8] = *(const float4*)src;
                }
            }
        __syncthreads();
        int ar = mw * 16 + (lane & 15);
        int asl = SWZ(ar, lane >> 4);
        f16x8 a0 = *(const f16x8*)&sA[ar * 32 + asl * 8];
        f16x8 a1 = *(const f16x8*)&sA[1024 + ar * 32 + asl * 8];
        f16x8 a2 = *(const f16x8*)&sA[2048 + ar * 32 + asl * 8];
#pragma unroll
        for (int g = 0; g < 3; ++g) {
            int br_ = g * 32 + hhalf * 16 + (lane & 15);
            int bsl = SWZ(br_, lane >> 4);
            f16x8 b0 = *(const f16x8*)&sW[br_ * 32 + bsl * 8];
            f16x8 b1 = *(const f16x8*)&sW[3072 + br_ * 32 + bsl * 8];
            f16x8 b2 = *(const f16x8*)&sW[6144 + br_ * 32 + bsl * 8];
            acc[g]  = __builtin_amdgcn_mfma_f32_16x16x32_f16(a0, b0, acc[g], 0, 0, 0);
            accx[g] = __builtin_amdgcn_mfma_f32_16x16x32_f16(a0, b1, accx[g], 0, 0, 0);
            accx[g] = __builtin_amdgcn_mfma_f32_16x16x32_f16(a1, b0, accx[g], 0, 0, 0);
            accy[g] = __builtin_amdgcn_mfma_f32_16x16x32_f16(a0, b2, accy[g], 0, 0, 0);
            accy[g] = __builtin_amdgcn_mfma_f32_16x16x32_f16(a1, b1, accy[g], 0, 0, 0);
            accy[g] = __builtin_amdgcn_mfma_f32_16x16x32_f16(a2, b0, accy[g], 0, 0, 0);
        }
        __syncthreads();
    }
}

// ---------------- one GRU layer for tile b (device) ----------------
__device__ void gru_block(
    int b,
    const f16* A0, const f16* A1, const f16* A2, int K1,
    const f16* Wi0, const f16* Wi1, const f16* Wi2,
    const f16* P0, const f16* P1, const f16* P2,
    const f16* Wh0, const f16* Wh1, const f16* Wh2,
    const float* bih, const float* bhh,
    const float* Hprevf, float* Hnewf,
    f16* O0, f16* O1, f16* O2,
    float* hsq_zero, float* hsq_acc, u64* amax_zero,
    f16* smem) {
    f16* sA = smem;            // 3*32*32
    f16* sW = smem + 3072;     // 3*96*32
    int tid = threadIdx.x;
    int lane = tid & 63;
    int wave = tid >> 6;
    int mw = wave & 1;
    int hhalf = wave >> 1;
    int c0i = b & 7;
    int c0 = c0i * 32;
    int m0 = (b >> 3) * 32;

    if (hsq_zero && c0i == 0 && tid < 32) hsq_zero[m0 + tid] = 0.0f;
    if (amax_zero && c0i == 0 && tid < 32) amax_zero[m0 + tid] = 0ull;

    f32x4 acc[3], accx[3], accy[3];
#pragma unroll
    for (int g = 0; g < 3; ++g) {
        acc[g] = (f32x4){0.f, 0.f, 0.f, 0.f};
        accx[g] = (f32x4){0.f, 0.f, 0.f, 0.f};
        accy[g] = (f32x4){0.f, 0.f, 0.f, 0.f};
    }

    gru_phase3(A0, A1, A2, Wi0, Wi1, Wi2, K1, m0, c0, tid, lane, mw, hhalf,
               acc, accx, accy, sA, sW);

    float gi[3][4];
#pragma unroll
    for (int g = 0; g < 3; ++g)
#pragma unroll
        for (int r = 0; r < 4; ++r) {
            gi[g][r] = acc[g][r] + accx[g][r] * S1 + accy[g][r] * S2;
            acc[g][r] = 0.f; accx[g][r] = 0.f; accy[g][r] = 0.f;
        }

    gru_phase3(P0, P1, P2, Wh0, Wh1, Wh2, 256, m0, c0, tid, lane, mw, hhalf,
               acc, accx, accy, sA, sW);

    int c = c0 + hhalf * 16 + (lane & 15);
    float br = bih[c] + bhh[c];
    float bz = bih[256 + c] + bhh[256 + c];
    float bni = bih[512 + c];
    float bnh = bhh[512 + c];
#pragma unroll
    for (int r = 0; r < 4; ++r) {
        int row = m0 + mw * 16 + (lane >> 4) * 4 + r;
        float gh_r = acc[0][r] + accx[0][r] * S1 + accy[0][r] * S2;
        float gh_z = acc[1][r] + accx[1][r] * S1 + accy[1][r] * S2;
        float gh_n = acc[2][r] + accx[2][r] * S1 + accy[2][r] * S2;
        float rg = 1.0f / (1.0f + expf(-(gi[0][r] + gh_r + br)));
        float zg = 1.0f / (1.0f + expf(-(gi[1][r] + gh_z + bz)));
        float ng = tanhf(gi[2][r] + bni + rg * (gh_n + bnh));
        float hp = Hprevf[(size_t)row * 256 + c];
        float o = (1.0f - zg) * ng + zg * hp;
        Hnewf[(size_t)row * 256 + c] = o;
        f16 q0, q1, q2;
        split3(o, q0, q1, q2);
        O0[(size_t)row * 256 + c] = q0;
        O1[(size_t)row * 256 + c] = q1;
        O2[(size_t)row * 256 + c] = q2;
        if (hsq_acc) {
            float sq = o * o;
#pragma unroll
            for (int off = 1; off < 16; off <<= 1) sq += __shfl_xor(sq, off);
            if ((lane & 15) == 0) atomicAdd(hsq_acc + row, sq);
        }
    }
}

// ---------------- scores + fused argmax for tile b (device) ----------------
__device__ void scores_block(
    int b,
    const f16* Ahh, const f16* All,
    const f16* W1h, const f16* W1l,
    const f16* W2h, const f16* W2l,
    const float* hsq, const float* be, const float* osq,
    float* out, u64* amax, f16* smem) {
    f16* sA = smem;            // 2 halves * 128 * 32
    f16* sB = smem + 8192;     // 4 arrays * 64 * 32
    int tid = threadIdx.x;
    int lane = tid & 63;
    int wave = tid >> 6;
    int wm = wave >> 1;
    int wn = wave & 1;
    int n0 = (b % 30) * 64;
    int m0 = (b / 30) * 128;

    f32x4 acc1[4][2], acc1x[4][2], acc2[4][2], acc2x[4][2];
#pragma unroll
    for (int i = 0; i < 4; ++i)
#pragma unroll
        for (int j = 0; j < 2; ++j) {
            acc1[i][j] = (f32x4){0.f, 0.f, 0.f, 0.f};
            acc1x[i][j] = (f32x4){0.f, 0.f, 0.f, 0.f};
            acc2[i][j] = (f32x4){0.f, 0.f, 0.f, 0.f};
            acc2x[i][j] = (f32x4){0.f, 0.f, 0.f, 0.f};
        }

    int rB = tid >> 2, slB = tid & 3;
    int gn = n0 + rB;
    bool okB = gn < NOPS;

    for (int k0 = 0; k0 < 256; k0 += 32) {
#pragma unroll
        for (int it = 0; it < 4; ++it) {
            const f16* src = (it < 2) ? Ahh : All;
            int r = (tid >> 2) + ((it & 1) << 6);
            int slt = tid & 3;
            float4 v = *(const float4*)(src + (size_t)(m0 + r) * 256 + k0 + slt * 8);
            *(float4*)&sA[(it >> 1) * 4096 + r * 32 + SWZ(r, slt) * 8] = v;
        }
#pragma unroll
        for (int it = 0; it < 4; ++it) {
            const f16* src = (it == 0) ? W1h : (it == 1) ? W1l : (it == 2) ? W2h : W2l;
            float4 v = make_float4(0.f, 0.f, 0.f, 0.f);
            if (okB) v = *(const float4*)(src + (size_t)gn * 256 + k0 + slB * 8);
            *(float4*)&sB[it * 2048 + rB * 32 + SWZ(rB, slB) * 8] = v;
        }
        __syncthreads();

        f16x8 ah[4], al[4];
#pragma unroll
        for (int fm = 0; fm < 4; ++fm) {
            int r = wm * 64 + fm * 16 + (lane & 15);
            int sl = SWZ(r, lane >> 4);
            ah[fm] = *(const f16x8*)&sA[r * 32 + sl * 8];
            al[fm] = *(const f16x8*)&sA[4096 + r * 32 + sl * 8];
        }
#pragma unroll
        for (int fn = 0; fn < 2; ++fn) {
            int r = wn * 32 + fn * 16 + (lane & 15);
            int sl = SWZ(r, lane >> 4);
            f16x8 b1h = *(const f16x8*)&sB[r * 32 + sl * 8];
            f16x8 b1l = *(const f16x8*)&sB[2048 + r * 32 + sl * 8];
            f16x8 b2h = *(const f16x8*)&sB[4096 + r * 32 + sl * 8];
            f16x8 b2l = *(const f16x8*)&sB[6144 + r * 32 + sl * 8];
#pragma unroll
            for (int fm = 0; fm < 4; ++fm) {
                acc1[fm][fn]  = __builtin_amdgcn_mfma_f32_16x16x32_f16(ah[fm], b1h, acc1[fm][fn], 0, 0, 0);
                acc1x[fm][fn] = __builtin_amdgcn_mfma_f32_16x16x32_f16(al[fm], b1h, acc1x[fm][fn], 0, 0, 0);
                acc1x[fm][fn] = __builtin_amdgcn_mfma_f32_16x16x32_f16(ah[fm], b1l, acc1x[fm][fn], 0, 0, 0);
                acc2[fm][fn]  = __builtin_amdgcn_mfma_f32_16x16x32_f16(ah[fm], b2h, acc2[fm][fn], 0, 0, 0);
                acc2x[fm][fn] = __builtin_amdgcn_mfma_f32_16x16x32_f16(al[fm], b2h, acc2x[fm][fn], 0, 0, 0);
                acc2x[fm][fn] = __builtin_amdgcn_mfma_f32_16x16x32_f16(ah[fm], b2l, acc2x[fm][fn], 0, 0, 0);
            }
        }
        __syncthreads();
    }

    const float inv = 1.0f / 1024.0f;
    int nn[2]; float bev[2], osv[2]; bool okn[2];
#pragma unroll
    for (int fn = 0; fn < 2; ++fn) {
        nn[fn] = n0 + wn * 32 + fn * 16 + (lane & 15);
        okn[fn] = nn[fn] < NOPS;
        bev[fn] = okn[fn] ? be[nn[fn]] : 0.0f;
        osv[fn] = okn[fn] ? osq[nn[fn]] : 0.0f;
    }
#pragma unroll
    for (int fm = 0; fm < 4; ++fm) {
#pragma unroll
        for (int r = 0; r < 4; ++r) {
            int m = m0 + wm * 64 + fm * 16 + (lane >> 4) * 4 + r;
            float hs = hsq[m];
            u64 bestk = 0ull;
#pragma unroll
            for (int fn = 0; fn < 2; ++fn) {
                if (okn[fn]) {
                    float dot1 = acc1[fm][fn][r] + acc1x[fm][fn][r] * inv;
                    float dot2 = acc2[fm][fn][r] + acc2x[fm][fn][r] * inv;
                    float sc = (dot1 + bev[fn])
                             - 0.5f * sqrtf(fmaxf(hs + osv[fn] - 2.0f * dot2, 0.0f));
                    out[(size_t)m * NOPS + nn[fn]] = sc;
                    unsigned int u = __float_as_uint(sc);
                    unsigned int mono = (u & 0x80000000u) ? ~u : (u | 0x80000000u);
                    u64 key = ((u64)mono << 32) | (u64)(0xFFFFFFFFu - (unsigned)nn[fn]);
                    if (key > bestk) bestk = key;
                }
            }
#pragma unroll
            for (int off = 1; off < 16; off <<= 1) {
                u64 ok = __shfl_xor(bestk, off);
                if (ok > bestk) bestk = ok;
            }
            if ((lane & 15) == 0) atomicMax(amax + m, bestk);
        }
    }
}

// ---------------- proj for tile b (+ traj write) (device) ----------------
__device__ void proj_block(
    int b,
    const f16* H0, const f16* H1, const f16* H2,
    const f16* E0, const f16* E1, const f16* E2,
    const u64* amax,
    const f16* W0, const f16* W1, const f16* W2,
    const float* bp,
    f16* X0, f16* X1, f16* X2,
    float* traj, f16* smem) {
    f16* sA = smem;            // 3*32*32
    f16* sB = smem + 3072;     // 3*64*32
    int tid = threadIdx.x;
    int lane = tid & 63;
    int wave = tid >> 6;
    int mw = wave & 1;
    int nh = wave >> 1;
    int n0 = (b % 5) * 64;
    int m0 = (b / 5) * 32;

    if ((b % 5) == 0 && tid < 32) {
        int row = m0 + tid;
        unsigned int selv = 0xFFFFFFFFu - (unsigned int)(amax[row] & 0xFFFFFFFFull);
        traj[row] = (float)selv;
    }

    f32x4 acc[2], accx[2], accy[2];
#pragma unroll
    for (int j = 0; j < 2; ++j) {
        acc[j] = (f32x4){0.f, 0.f, 0.f, 0.f};
        accx[j] = (f32x4){0.f, 0.f, 0.f, 0.f};
        accy[j] = (f32x4){0.f, 0.f, 0.f, 0.f};
    }

    for (int k0 = 0; k0 < 512; k0 += 32) {
#pragma unroll
        for (int it = 0; it < 2; ++it) {
            int flat = tid + 256 * it;
            if (flat < 384) {
                int third = flat >> 7;
                int within = flat & 127;
                int row = within >> 2, slot = within & 3;
                int gr = m0 + row;
                const f16* src;
                if (k0 < 256) {
                    const f16* base = (third == 0 ? H0 : third == 1 ? H1 : H2);
                    src = base + (size_t)gr * 256 + k0 + slot * 8;
                } else {
                    unsigned int selv = 0xFFFFFFFFu - (unsigned int)(amax[gr] & 0xFFFFFFFFull);
                    const f16* base = (third == 0 ? E0 : third == 1 ? E1 : E2);
                    src = base + (size_t)selv * 256 + (k0 - 256) + slot * 8;
                }
                *(float4*)&sA[third * 1024 + row * 32 + SWZ(row, slot) * 8] = *(const float4*)src;
            }
        }
#pragma unroll
        for (int third = 0; third < 3; ++third) {
            int row = tid >> 2, slot = tid & 3;
            const f16* src = (third == 0 ? W0 : third == 1 ? W1 : W2)
                             + (size_t)(n0 + row) * 512 + k0 + slot * 8;
            *(float4*)&sB[third * 2048 + row * 32 + SWZ(row, slot) * 8] = *(const float4*)src;
        }
        __syncthreads();
        int ar = mw * 16 + (lane & 15);
        int asl = SWZ(ar, lane >> 4);
        f16x8 a0 = *(const f16x8*)&sA[ar * 32 + asl * 8];
        f16x8 a1 = *(const f16x8*)&sA[1024 + ar * 32 + asl * 8];
        f16x8 a2 = *(const f16x8*)&sA[2048 + ar * 32 + asl * 8];
#pragma unroll
        for (int j = 0; j < 2; ++j) {
            int brr = (nh * 2 + j) * 16 + (lane & 15);
            int bsl = SWZ(brr, lane >> 4);
            f16x8 b0 = *(const f16x8*)&sB[brr * 32 + bsl * 8];
            f16x8 b1 = *(const f16x8*)&sB[2048 + brr * 32 + bsl * 8];
            f16x8 b2 = *(const f16x8*)&sB[4096 + brr * 32 + bsl * 8];
            acc[j]  = __builtin_amdgcn_mfma_f32_16x16x32_f16(a0, b0, acc[j], 0, 0, 0);
            accx[j] = __builtin_amdgcn_mfma_f32_16x16x32_f16(a0, b1, accx[j], 0, 0, 0);
            accx[j] = __builtin_amdgcn_mfma_f32_16x16x32_f16(a1, b0, accx[j], 0, 0, 0);
            accy[j] = __builtin_amdgcn_mfma_f32_16x16x32_f16(a0, b2, accy[j], 0, 0, 0);
            accy[j] = __builtin_amdgcn_mfma_f32_16x16x32_f16(a1, b1, accy[j], 0, 0, 0);
            accy[j] = __builtin_amdgcn_mfma_f32_16x16x32_f16(a2, b0, accy[j], 0, 0, 0);
        }
        __syncthreads();
    }

#pragma unroll
    for (int j = 0; j < 2; ++j) {
        int n = n0 + (nh * 2 + j) * 16 + (lane & 15);
        float bv = bp[n];
#pragma unroll
        for (int r = 0; r < 4; ++r) {
            int m = m0 + mw * 16 + (lane >> 4) * 4 + r;
            float o = acc[j][r] + accx[j][r] * S1 + accy[j][r] * S2 + bv;
            f16 q0, q1, q2;
            split3(o, q0, q1, q2);
            X0[(size_t)m * 320 + n] = q0;
            X1[(size_t)m * 320 + n] = q1;
            X2[(size_t)m * 320 + n] = q2;
        }
    }
}

// ---------------- persistent 20-step loop ----------------
struct MegaP {
    f16 *x0, *x1, *x2;
    const f16 *wi0a, *wi0b, *wi0c, *wh0a, *wh0b, *wh0c;
    const f16 *wi1a, *wi1b, *wi1c, *wh1a, *wh1b, *wh1c;
    const f16 *wpa, *wpb, *wpc;
    const f16 *emba, *embb, *embc;
    const f16 *weh, *wel, *oph, *opl;
    const float *bih0, *bhh0, *bih1, *bhh1, *be, *bp, *osq;
    float *h0f[2], *h1f[2];
    f16 *h0c[2][3], *h1c[2][3];
    float *hsq;
    u64 *amax;
    unsigned *cnt;
    float *traj, *scores;
};

__global__ __launch_bounds__(256, 2) void megakernel(MegaP P) {
    __shared__ __align__(16) f16 smem[16384];   // 32 KiB union
    int b = blockIdx.x;
    unsigned ep = 0;
    for (int t = 0; t < STEPS; ++t) {
        int pi = t & 1, po = pi ^ 1;

        gru_block(b, P.x0, P.x1, P.x2, INDIM,
                  P.wi0a, P.wi0b, P.wi0c,
                  P.h0c[pi][0], P.h0c[pi][1], P.h0c[pi][2],
                  P.wh0a, P.wh0b, P.wh0c,
                  P.bih0, P.bhh0, P.h0f[pi], P.h0f[po],
                  P.h0c[po][0], P.h0c[po][1], P.h0c[po][2],
                  P.hsq, nullptr, nullptr, smem);
        gridbar(P.cnt, (++ep) * GRIDN);

        gru_block(b, P.h0c[po][0], P.h0c[po][1], P.h0c[po][2], 256,
                  P.wi1a, P.wi1b, P.wi1c,
                  P.h1c[pi][0], P.h1c[pi][1], P.h1c[pi][2],
                  P.wh1a, P.wh1b, P.wh1c,
                  P.bih1, P.bhh1, P.h1f[pi], P.h1f[po],
                  P.h1c[po][0], P.h1c[po][1], P.h1c[po][2],
                  nullptr, P.hsq, P.amax, smem);
        gridbar(P.cnt, (++ep) * GRIDN);

        if (b < 480)
            scores_block(b, P.h1c[po][0], P.h1c[po][1],
                         P.weh, P.wel, P.oph, P.opl,
                         P.hsq, P.be, P.osq,
                         P.scores + (size_t)t * B * NOPS, P.amax, smem);
        gridbar(P.cnt, (++ep) * GRIDN);

        if (b < 320)
            proj_block(b, P.h1c[po][0], P.h1c[po][1], P.h1c[po][2],
                       P.emba, P.embb, P.embc, P.amax,
                       P.wpa, P.wpb, P.wpc, P.bp,
                       P.x0, P.x1, P.x2,
                       P.traj + (size_t)t * B, smem);
        gridbar(P.cnt, (++ep) * GRIDN);
    }
}

extern "C" void kernel_launch(void* const* d_in, const int* in_sizes, int n_in,
                              void* d_out, int out_size, void* d_ws, size_t ws_size,
                              hipStream_t stream) {
    const float* geo      = (const float*)d_in[0];
    const float* sem      = (const float*)d_in[1];
    const float* w_ih0    = (const float*)d_in[2];
    const float* w_hh0    = (const float*)d_in[3];
    const float* b_ih0    = (const float*)d_in[4];
    const float* b_hh0    = (const float*)d_in[5];
    const float* w_ih1    = (const float*)d_in[6];
    const float* w_hh1    = (const float*)d_in[7];
    const float* b_ih1    = (const float*)d_in[8];
    const float* b_hh1    = (const float*)d_in[9];
    const float* w_energy = (const float*)d_in[10];
    const float* b_energy = (const float*)d_in[11];
    const float* w_proj   = (const float*)d_in[12];
    const float* b_proj   = (const float*)d_in[13];
    const float* w_op     = (const float*)d_in[14];
    const float* op_emb   = (const float*)d_in[15];

    char* p = (char*)d_ws;
    auto alloc = [&](size_t bytes) { char* q = p; p += (bytes + 255) & ~255ULL; return q; };
    float* opp   = (float*)alloc((size_t)NOPS * 256 * 4);
    float* oppsq = (float*)alloc((size_t)NOPS * 4);
    float* hsq   = (float*)alloc((size_t)B * 4);
    u64*   amax  = (u64*)  alloc((size_t)B * 8);
    unsigned* cnt = (unsigned*)alloc(256);
    float *h0f[2], *h1f[2];
    f16 *h0c[2][3], *h1c[2][3];
    for (int i = 0; i < 2; ++i) {
        h0f[i] = (float*)alloc((size_t)B * H * 4);
        h1f[i] = (float*)alloc((size_t)B * H * 4);
        for (int j = 0; j < 3; ++j) {
            h0c[i][j] = (f16*)alloc((size_t)B * H * 2);
            h1c[i][j] = (f16*)alloc((size_t)B * H * 2);
        }
    }
    f16* x0 = (f16*)alloc((size_t)B * INDIM * 2);
    f16* x1 = (f16*)alloc((size_t)B * INDIM * 2);
    f16* x2 = (f16*)alloc((size_t)B * INDIM * 2);
    f16 *wi0[3], *wh0[3], *wi1[3], *wh1[3], *wp[3], *emb[3];
    for (int i = 0; i < 3; ++i) {
        wi0[i] = (f16*)alloc((size_t)768 * 320 * 2);
        wh0[i] = (f16*)alloc((size_t)768 * 256 * 2);
        wi1[i] = (f16*)alloc((size_t)768 * 256 * 2);
        wh1[i] = (f16*)alloc((size_t)768 * 256 * 2);
        wp[i]  = (f16*)alloc((size_t)320 * 512 * 2);
        emb[i] = (f16*)alloc((size_t)NOPS * 256 * 2);
    }
    f16* weh = (f16*)alloc((size_t)NOPS * 256 * 2);
    f16* wel = (f16*)alloc((size_t)NOPS * 256 * 2);
    f16* oph = (f16*)alloc((size_t)NOPS * 256 * 2);
    f16* opl = (f16*)alloc((size_t)NOPS * 256 * 2);

    float* out    = (float*)d_out;
    float* traj   = out;
    float* scores = out + (size_t)STEPS * B;

    init_kernel<<<dim3((B * INDIM + 255) / 256), dim3(256), 0, stream>>>(
        geo, sem, x0, x1, x2, h0f[0], h1f[0],
        h0c[0][0], h0c[0][1], h0c[0][2], h1c[0][0], h1c[0][1], h1c[0][2],
        hsq, amax, cnt);
    gemm_tn<<<dim3(256 / BN, (NOPS + BM - 1) / BM), dim3(256), 0, stream>>>(
        op_emb, w_op, nullptr, opp, NOPS, 256, 256);
    cvt3_rows<<<dim3(192), dim3(256), 0, stream>>>(w_ih0, 768, 320, wi0[0], wi0[1], wi0[2]);
    cvt3_rows<<<dim3(192), dim3(256), 0, stream>>>(w_hh0, 768, 256, wh0[0], wh0[1], wh0[2]);
    cvt3_rows<<<dim3(192), dim3(256), 0, stream>>>(w_ih1, 768, 256, wi1[0], wi1[1], wi1[2]);
    cvt3_rows<<<dim3(192), dim3(256), 0, stream>>>(w_hh1, 768, 256, wh1[0], wh1[1], wh1[2]);
    cvt3_rows<<<dim3(80), dim3(256), 0, stream>>>(w_proj, 320, 512, wp[0], wp[1], wp[2]);
    cvt3_rows<<<dim3((NOPS + 3) / 4), dim3(256), 0, stream>>>(op_emb, NOPS, 256, emb[0], emb[1], emb[2]);
    cvt_rows<<<dim3((NOPS + 3) / 4), dim3(256), 0, stream>>>(w_energy, NOPS, 256, weh, wel, nullptr);
    cvt_rows<<<dim3((NOPS + 3) / 4), dim3(256), 0, stream>>>(opp, NOPS, 256, oph, opl, oppsq);

    MegaP P;
    P.x0 = x0; P.x1 = x1; P.x2 = x2;
    P.wi0a = wi0[0]; P.wi0b = wi0[1]; P.wi0c = wi0[2];
    P.wh0a = wh0[0]; P.wh0b = wh0[1]; P.wh0c = wh0[2];
    P.wi1a = wi1[0]; P.wi1b = wi1[1]; P.wi1c = wi1[2];
    P.wh1a = wh1[0]; P.wh1b = wh1[1]; P.wh1c = wh1[2];
    P.wpa = wp[0]; P.wpb = wp[1]; P.wpc = wp[2];
    P.emba = emb[0]; P.embb = emb[1]; P.embc = emb[2];
    P.weh = weh; P.wel = wel; P.oph = oph; P.opl = opl;
    P.bih0 = b_ih0; P.bhh0 = b_hh0; P.bih1 = b_ih1; P.bhh1 = b_hh1;
    P.be = b_energy; P.bp = b_proj; P.osq = oppsq;
    for (int i = 0; i < 2; ++i) {
        P.h0f[i] = h0f[i]; P.h1f[i] = h1f[i];
        for (int j = 0; j < 3; ++j) { P.h0c[i][j] = h0c[i][j]; P.h1c[i][j] = h1c[i][j]; }
    }
    P.hsq = hsq; P.amax = amax; P.cnt = cnt;
    P.traj = traj; P.scores = scores;

    megakernel<<<dim3(GRIDN), dim3(256), 0, stream>>>(P);
}

// Round 6
// 2524.547 us; speedup vs baseline: 4.8020x; 4.8020x over previous
//
#include <hip/hip_runtime.h>
#include <math.h>

#define B 2048
#define H 256
#define INDIM 320
#define NOPS 1883
#define STEPS 20

typedef _Float16 f16;
typedef _Float16 f16x4 __attribute__((ext_vector_type(4)));
typedef _Float16 f16x8 __attribute__((ext_vector_type(8)));
typedef float f32x4 __attribute__((ext_vector_type(4)));
typedef unsigned long long u64;

// XOR swizzle: 4 16B-slots per 64B (32-f16) row; bijective involution per row.
#define SWZ(r, s) ((s) ^ ((r) & 3) ^ (((r) >> 2) & 1))

#define S1 (1.0f / 1024.0f)
#define S2 (1.0f / 1048576.0f)

__device__ __forceinline__ void split3(float f, f16& c0, f16& c1, f16& c2) {
    c0 = (f16)f;
    float r1 = f - (float)c0;
    c1 = (f16)(r1 * 1024.0f);
    float r2 = r1 - (float)c1 * S1;
    c2 = (f16)(r2 * 1048576.0f);
}

// ---------------- init: x = concat(geo,sem) triple-split; zero h state + reductions ---
__global__ __launch_bounds__(256) void init_kernel(const float* __restrict__ geo,
                                                   const float* __restrict__ sem,
                                                   f16* __restrict__ x0, f16* __restrict__ x1,
                                                   f16* __restrict__ x2,
                                                   float* __restrict__ h0f, float* __restrict__ h1f,
                                                   f16* __restrict__ h0c0, f16* __restrict__ h0c1,
                                                   f16* __restrict__ h0c2,
                                                   f16* __restrict__ h1c0, f16* __restrict__ h1c1,
                                                   f16* __restrict__ h1c2,
                                                   float* __restrict__ hsq, u64* __restrict__ amax) {
    int i = blockIdx.x * blockDim.x + threadIdx.x;
    if (i < B * INDIM) {
        int b = i / INDIM, c = i % INDIM;
        float f = (c < 256) ? geo[b * 256 + c] : sem[b * 64 + (c - 256)];
        f16 a, bb, cc;
        split3(f, a, bb, cc);
        x0[i] = a; x1[i] = bb; x2[i] = cc;
    }
    if (i < B * H) {
        h0f[i] = 0.0f; h1f[i] = 0.0f;
        h0c0[i] = (f16)0.0f; h0c1[i] = (f16)0.0f; h0c2[i] = (f16)0.0f;
        h1c0[i] = (f16)0.0f; h1c1[i] = (f16)0.0f; h1c2[i] = (f16)0.0f;
    }
    if (i < B) { hsq[i] = 0.0f; amax[i] = 0ull; }
}

// ---------------- generic tiled GEMM (used only for opp precompute) ----------------
#define BM 64
#define BN 64
#define BK 16
__global__ __launch_bounds__(256) void gemm_tn(const float* __restrict__ A,
                                               const float* __restrict__ Bm,
                                               const float* __restrict__ bias,
                                               float* __restrict__ C,
                                               int M, int N, int K) {
    __shared__ float As[BK][BM];
    __shared__ float Bs[BK][BN];
    int tid = threadIdx.x;
    int bm0 = blockIdx.y * BM;
    int bn0 = blockIdx.x * BN;
    int tx = tid & 15, ty = tid >> 4;
    int lr = tid >> 2;
    int lk = (tid & 3) << 2;

    float acc[4][4];
#pragma unroll
    for (int i = 0; i < 4; ++i)
#pragma unroll
        for (int j = 0; j < 4; ++j) acc[i][j] = 0.0f;

    for (int k0 = 0; k0 < K; k0 += BK) {
        {
            int gr = bm0 + lr;
            float4 v = make_float4(0.f, 0.f, 0.f, 0.f);
            if (gr < M) v = *(const float4*)(A + (size_t)gr * K + k0 + lk);
            As[lk + 0][lr] = v.x; As[lk + 1][lr] = v.y;
            As[lk + 2][lr] = v.z; As[lk + 3][lr] = v.w;
        }
        {
            int gn = bn0 + lr;
            float4 v = make_float4(0.f, 0.f, 0.f, 0.f);
            if (gn < N) v = *(const float4*)(Bm + (size_t)gn * K + k0 + lk);
            Bs[lk + 0][lr] = v.x; Bs[lk + 1][lr] = v.y;
            Bs[lk + 2][lr] = v.z; Bs[lk + 3][lr] = v.w;
        }
        __syncthreads();
#pragma unroll
        for (int k = 0; k < BK; ++k) {
            float a[4], b[4];
#pragma unroll
            for (int i = 0; i < 4; ++i) a[i] = As[k][ty * 4 + i];
#pragma unroll
            for (int j = 0; j < 4; ++j) b[j] = Bs[k][tx * 4 + j];
#pragma unroll
            for (int i = 0; i < 4; ++i)
#pragma unroll
                for (int j = 0; j < 4; ++j) acc[i][j] = fmaf(a[i], b[j], acc[i][j]);
        }
        __syncthreads();
    }
#pragma unroll
    for (int i = 0; i < 4; ++i) {
        int gr = bm0 + ty * 4 + i;
        if (gr >= M) continue;
#pragma unroll
        for (int j = 0; j < 4; ++j) {
            int gc = bn0 + tx * 4 + j;
            if (gc < N) C[(size_t)gr * N + gc] = acc[i][j] + (bias ? bias[gc] : 0.0f);
        }
    }
}

// ---------------- fp32 -> fp16 hi/lo double split (lo x1024) + optional row sumsq -----
__global__ __launch_bounds__(256) void cvt_rows(const float* __restrict__ A, int rows, int cols,
                                                f16* __restrict__ hi, f16* __restrict__ lo,
                                                float* __restrict__ sq) {
    int row = blockIdx.x * 4 + (threadIdx.x >> 6);
    int lane = threadIdx.x & 63;
    if (row >= rows) return;
    const float* src = A + (size_t)row * cols;
    float s = 0.0f;
    for (int c0 = 0; c0 < cols; c0 += 256) {
        int idx = c0 + lane * 4;
        if (idx < cols) {
            float4 v = *(const float4*)(src + idx);
            float vv[4] = {v.x, v.y, v.z, v.w};
            f16x4 h, l;
#pragma unroll
            for (int j = 0; j < 4; ++j) {
                float f = vv[j];
                f16 hv = (f16)f;
                h[j] = hv;
                l[j] = (f16)((f - (float)hv) * 1024.0f);
                s = fmaf(f, f, s);
            }
            *(f16x4*)(hi + (size_t)row * cols + idx) = h;
            *(f16x4*)(lo + (size_t)row * cols + idx) = l;
        }
    }
    if (sq) {
#pragma unroll
        for (int off = 32; off > 0; off >>= 1) s += __shfl_down(s, off);
        if (lane == 0) sq[row] = s;
    }
}

// ---------------- fp32 -> fp16 triple split ----------------
__global__ __launch_bounds__(256) void cvt3_rows(const float* __restrict__ A, int rows, int cols,
                                                 f16* __restrict__ o0, f16* __restrict__ o1,
                                                 f16* __restrict__ o2) {
    int row = blockIdx.x * 4 + (threadIdx.x >> 6);
    int lane = threadIdx.x & 63;
    if (row >= rows) return;
    const float* src = A + (size_t)row * cols;
    for (int c0 = 0; c0 < cols; c0 += 256) {
        int idx = c0 + lane * 4;
        if (idx < cols) {
            float4 v = *(const float4*)(src + idx);
            float vv[4] = {v.x, v.y, v.z, v.w};
            f16x4 a, b, c;
#pragma unroll
            for (int j = 0; j < 4; ++j) {
                f16 p, q, r;
                split3(vv[j], p, q, r);
                a[j] = p; b[j] = q; c[j] = r;
            }
            *(f16x4*)(o0 + (size_t)row * cols + idx) = a;
            *(f16x4*)(o1 + (size_t)row * cols + idx) = b;
            *(f16x4*)(o2 + (size_t)row * cols + idx) = c;
        }
    }
}

// ---------------- triple-split MFMA GRU layer (M=64, 512 threads, K-chunk 64) ---------
// grid (H/32=8, B/64=32) = 256 blocks x 8 waves. wave: mfrag = w&3, hhalf = w>>2.
// LDS: sA [third 3][kslot 2][row 64][32], sW [third 3][kslot 2][row 96][32]  = 60 KiB.
__device__ __forceinline__ void gru_phase3(
    const f16* __restrict__ A0, const f16* __restrict__ A1, const f16* __restrict__ A2,
    const f16* __restrict__ W0, const f16* __restrict__ W1, const f16* __restrict__ W2,
    int K, int m0, int c0, int tid, int lane, int mfrag, int hhalf,
    f32x4* acc, f32x4* accx, f32x4* accy, f16* sA, f16* sW) {
    for (int k0 = 0; k0 < K; k0 += 64) {
        // stage A: 3 thirds x 2 kslots x 64 rows x 4 slots = 1536 float4 (3 passes)
#pragma unroll
        for (int it = 0; it < 3; ++it) {
            int idx = tid + 512 * it;
            int third = idx >> 9;
            int rem = idx & 511;
            int kslot = rem >> 8;
            int within = rem & 255;
            int row = within >> 2, slot = within & 3;
            const f16* src = (third == 0 ? A0 : third == 1 ? A1 : A2)
                             + (size_t)(m0 + row) * K + k0 + kslot * 32 + slot * 8;
            *(float4*)&sA[third * 4096 + kslot * 2048 + row * 32 + SWZ(row, slot) * 8] =
                *(const float4*)src;
        }
        // stage W: 3 x 2 x 96 x 4 = 2304 float4 (4.5 passes)
#pragma unroll
        for (int it = 0; it < 5; ++it) {
            int idx = tid + 512 * it;
            if (idx < 2304) {
                int third = idx / 768;
                int rem = idx - third * 768;
                int kslot = rem / 384;
                int within = rem - kslot * 384;
                int row = within >> 2, slot = within & 3;
                int wr = ((row >> 5) << 8) + c0 + (row & 31);
                const f16* src = (third == 0 ? W0 : third == 1 ? W1 : W2)
                                 + (size_t)wr * K + k0 + kslot * 32 + slot * 8;
                *(float4*)&sW[third * 6144 + kslot * 3072 + row * 32 + SWZ(row, slot) * 8] =
                    *(const float4*)src;
            }
        }
        __syncthreads();
#pragma unroll
        for (int kslot = 0; kslot < 2; ++kslot) {
            int ar = mfrag * 16 + (lane & 15);
            int asl = SWZ(ar, lane >> 4);
            f16x8 a0 = *(const f16x8*)&sA[kslot * 2048 + ar * 32 + asl * 8];
            f16x8 a1 = *(const f16x8*)&sA[4096 + kslot * 2048 + ar * 32 + asl * 8];
            f16x8 a2 = *(const f16x8*)&sA[8192 + kslot * 2048 + ar * 32 + asl * 8];
#pragma unroll
            for (int g = 0; g < 3; ++g) {
                int br_ = g * 32 + hhalf * 16 + (lane & 15);
                int bsl = SWZ(br_, lane >> 4);
                f16x8 b0 = *(const f16x8*)&sW[kslot * 3072 + br_ * 32 + bsl * 8];
                f16x8 b1 = *(const f16x8*)&sW[6144 + kslot * 3072 + br_ * 32 + bsl * 8];
                f16x8 b2 = *(const f16x8*)&sW[12288 + kslot * 3072 + br_ * 32 + bsl * 8];
                acc[g]  = __builtin_amdgcn_mfma_f32_16x16x32_f16(a0, b0, acc[g], 0, 0, 0);
                accx[g] = __builtin_amdgcn_mfma_f32_16x16x32_f16(a0, b1, accx[g], 0, 0, 0);
                accx[g] = __builtin_amdgcn_mfma_f32_16x16x32_f16(a1, b0, accx[g], 0, 0, 0);
                accy[g] = __builtin_amdgcn_mfma_f32_16x16x32_f16(a0, b2, accy[g], 0, 0, 0);
                accy[g] = __builtin_amdgcn_mfma_f32_16x16x32_f16(a1, b1, accy[g], 0, 0, 0);
                accy[g] = __builtin_amdgcn_mfma_f32_16x16x32_f16(a2, b0, accy[g], 0, 0, 0);
            }
        }
        __syncthreads();
    }
}

__global__ __launch_bounds__(512) void gru_mfma3(
    const f16* __restrict__ A0, const f16* __restrict__ A1, const f16* __restrict__ A2, int K1,
    const f16* __restrict__ Wi0, const f16* __restrict__ Wi1, const f16* __restrict__ Wi2,
    const f16* __restrict__ P0, const f16* __restrict__ P1, const f16* __restrict__ P2,
    const f16* __restrict__ Wh0, const f16* __restrict__ Wh1, const f16* __restrict__ Wh2,
    const float* __restrict__ bih, const float* __restrict__ bhh,
    const float* __restrict__ Hprevf,
    float* __restrict__ Hnewf,
    f16* __restrict__ O0, f16* __restrict__ O1, f16* __restrict__ O2,
    float* __restrict__ hsq_zero, float* __restrict__ hsq_acc,
    u64* __restrict__ amax_zero) {
    __shared__ __align__(16) f16 sA[3 * 2 * 64 * 32];   // 24 KiB
    __shared__ __align__(16) f16 sW[3 * 2 * 96 * 32];   // 36 KiB
    int tid = threadIdx.x;
    int lane = tid & 63;
    int wave = tid >> 6;
    int mfrag = wave & 3;
    int hhalf = wave >> 2;
    int c0 = blockIdx.x * 32;
    int m0 = blockIdx.y * 64;

    if (hsq_zero && blockIdx.x == 0 && tid < 64) hsq_zero[m0 + tid] = 0.0f;
    if (amax_zero && blockIdx.x == 0 && tid < 64) amax_zero[m0 + tid] = 0ull;

    f32x4 acc[3], accx[3], accy[3];
#pragma unroll
    for (int g = 0; g < 3; ++g) {
        acc[g] = (f32x4){0.f, 0.f, 0.f, 0.f};
        accx[g] = (f32x4){0.f, 0.f, 0.f, 0.f};
        accy[g] = (f32x4){0.f, 0.f, 0.f, 0.f};
    }

    gru_phase3(A0, A1, A2, Wi0, Wi1, Wi2, K1, m0, c0, tid, lane, mfrag, hhalf,
               acc, accx, accy, sA, sW);

    float gi[3][4];
#pragma unroll
    for (int g = 0; g < 3; ++g)
#pragma unroll
        for (int r = 0; r < 4; ++r) {
            gi[g][r] = acc[g][r] + accx[g][r] * S1 + accy[g][r] * S2;
            acc[g][r] = 0.f; accx[g][r] = 0.f; accy[g][r] = 0.f;
        }

    gru_phase3(P0, P1, P2, Wh0, Wh1, Wh2, 256, m0, c0, tid, lane, mfrag, hhalf,
               acc, accx, accy, sA, sW);

    int c = c0 + hhalf * 16 + (lane & 15);
    float br = bih[c] + bhh[c];
    float bz = bih[256 + c] + bhh[256 + c];
    float bni = bih[512 + c];
    float bnh = bhh[512 + c];
#pragma unroll
    for (int r = 0; r < 4; ++r) {
        int row = m0 + mfrag * 16 + (lane >> 4) * 4 + r;
        float gh_r = acc[0][r] + accx[0][r] * S1 + accy[0][r] * S2;
        float gh_z = acc[1][r] + accx[1][r] * S1 + accy[1][r] * S2;
        float gh_n = acc[2][r] + accx[2][r] * S1 + accy[2][r] * S2;
        float rg = 1.0f / (1.0f + expf(-(gi[0][r] + gh_r + br)));
        float zg = 1.0f / (1.0f + expf(-(gi[1][r] + gh_z + bz)));
        float ng = tanhf(gi[2][r] + bni + rg * (gh_n + bnh));
        float hp = Hprevf[(size_t)row * 256 + c];
        float o = (1.0f - zg) * ng + zg * hp;
        Hnewf[(size_t)row * 256 + c] = o;
        f16 q0, q1, q2;
        split3(o, q0, q1, q2);
        O0[(size_t)row * 256 + c] = q0;
        O1[(size_t)row * 256 + c] = q1;
        O2[(size_t)row * 256 + c] = q2;
        if (hsq_acc) {
            float sq = o * o;
#pragma unroll
            for (int off = 1; off < 16; off <<= 1) sq += __shfl_xor(sq, off);
            if ((lane & 15) == 0) atomicAdd(hsq_acc + row, sq);
        }
    }
}

// ---------------- MFMA split-fp16 scores + fused argmax (K-chunk 64) ------------------
// LDS: sA [half 2][kslot 2][128][32] = 32 KiB; sB [arr 4][kslot 2][64][32] = 32 KiB.
__global__ __launch_bounds__(256, 2) void scores_mfma(
    const f16* __restrict__ Ahh, const f16* __restrict__ All,
    const f16* __restrict__ W1h, const f16* __restrict__ W1l,
    const f16* __restrict__ W2h, const f16* __restrict__ W2l,
    const float* __restrict__ hsq, const float* __restrict__ be,
    const float* __restrict__ osq, float* __restrict__ out,
    u64* __restrict__ amax) {
    __shared__ __align__(16) f16 sA[2 * 2 * 128 * 32];
    __shared__ __align__(16) f16 sB[4 * 2 * 64 * 32];
    int tid = threadIdx.x;
    int lane = tid & 63;
    int wave = tid >> 6;
    int wm = wave >> 1;
    int wn = wave & 1;
    int n0 = blockIdx.x * 64;
    int m0 = blockIdx.y * 128;

    f32x4 acc1[4][2], acc1x[4][2], acc2[4][2], acc2x[4][2];
#pragma unroll
    for (int i = 0; i < 4; ++i)
#pragma unroll
        for (int j = 0; j < 2; ++j) {
            acc1[i][j] = (f32x4){0.f, 0.f, 0.f, 0.f};
            acc1x[i][j] = (f32x4){0.f, 0.f, 0.f, 0.f};
            acc2[i][j] = (f32x4){0.f, 0.f, 0.f, 0.f};
            acc2x[i][j] = (f32x4){0.f, 0.f, 0.f, 0.f};
        }

    for (int k0 = 0; k0 < 256; k0 += 64) {
        // stage A: 2 halves x 2 kslots x 128 rows x 4 slots = 2048 float4 (8 passes)
#pragma unroll
        for (int it = 0; it < 8; ++it) {
            int idx = tid + 256 * it;
            int half = idx >> 10;
            int rem = idx & 1023;
            int kslot = rem >> 9;
            int within = rem & 511;
            int r = within >> 2, slt = within & 3;
            const f16* src = (half ? All : Ahh)
                             + (size_t)(m0 + r) * 256 + k0 + kslot * 32 + slt * 8;
            *(float4*)&sA[half * 8192 + kslot * 4096 + r * 32 + SWZ(r, slt) * 8] =
                *(const float4*)src;
        }
        // stage B: 4 arrays x 2 kslots x 64 rows x 4 slots = 2048 float4 (8 passes)
#pragma unroll
        for (int it = 0; it < 8; ++it) {
            int idx = tid + 256 * it;
            int arr = idx >> 9;
            int rem = idx & 511;
            int kslot = rem >> 8;
            int within = rem & 255;
            int r = within >> 2, slt = within & 3;
            const f16* src = (arr == 0) ? W1h : (arr == 1) ? W1l : (arr == 2) ? W2h : W2l;
            int gn = n0 + r;
            float4 v = make_float4(0.f, 0.f, 0.f, 0.f);
            if (gn < NOPS) v = *(const float4*)(src + (size_t)gn * 256 + k0 + kslot * 32 + slt * 8);
            *(float4*)&sB[arr * 4096 + kslot * 2048 + r * 32 + SWZ(r, slt) * 8] = v;
        }
        __syncthreads();

#pragma unroll
        for (int kslot = 0; kslot < 2; ++kslot) {
            f16x8 ah[4], al[4];
#pragma unroll
            for (int fm = 0; fm < 4; ++fm) {
                int r = wm * 64 + fm * 16 + (lane & 15);
                int sl = SWZ(r, lane >> 4);
                ah[fm] = *(const f16x8*)&sA[kslot * 4096 + r * 32 + sl * 8];
                al[fm] = *(const f16x8*)&sA[8192 + kslot * 4096 + r * 32 + sl * 8];
            }
#pragma unroll
            for (int fn = 0; fn < 2; ++fn) {
                int r = wn * 32 + fn * 16 + (lane & 15);
                int sl = SWZ(r, lane >> 4);
                f16x8 b1h = *(const f16x8*)&sB[kslot * 2048 + r * 32 + sl * 8];
                f16x8 b1l = *(const f16x8*)&sB[4096 + kslot * 2048 + r * 32 + sl * 8];
                f16x8 b2h = *(const f16x8*)&sB[8192 + kslot * 2048 + r * 32 + sl * 8];
                f16x8 b2l = *(const f16x8*)&sB[12288 + kslot * 2048 + r * 32 + sl * 8];
#pragma unroll
                for (int fm = 0; fm < 4; ++fm) {
                    acc1[fm][fn]  = __builtin_amdgcn_mfma_f32_16x16x32_f16(ah[fm], b1h, acc1[fm][fn], 0, 0, 0);
                    acc1x[fm][fn] = __builtin_amdgcn_mfma_f32_16x16x32_f16(al[fm], b1h, acc1x[fm][fn], 0, 0, 0);
                    acc1x[fm][fn] = __builtin_amdgcn_mfma_f32_16x16x32_f16(ah[fm], b1l, acc1x[fm][fn], 0, 0, 0);
                    acc2[fm][fn]  = __builtin_amdgcn_mfma_f32_16x16x32_f16(ah[fm], b2h, acc2[fm][fn], 0, 0, 0);
                    acc2x[fm][fn] = __builtin_amdgcn_mfma_f32_16x16x32_f16(al[fm], b2h, acc2x[fm][fn], 0, 0, 0);
                    acc2x[fm][fn] = __builtin_amdgcn_mfma_f32_16x16x32_f16(ah[fm], b2l, acc2x[fm][fn], 0, 0, 0);
                }
            }
        }
        __syncthreads();
    }

    const float inv = 1.0f / 1024.0f;
    int nn[2]; float bev[2], osv[2]; bool okn[2];
#pragma unroll
    for (int fn = 0; fn < 2; ++fn) {
        nn[fn] = n0 + wn * 32 + fn * 16 + (lane & 15);
        okn[fn] = nn[fn] < NOPS;
        bev[fn] = okn[fn] ? be[nn[fn]] : 0.0f;
        osv[fn] = okn[fn] ? osq[nn[fn]] : 0.0f;
    }
#pragma unroll
    for (int fm = 0; fm < 4; ++fm) {
#pragma unroll
        for (int r = 0; r < 4; ++r) {
            int m = m0 + wm * 64 + fm * 16 + (lane >> 4) * 4 + r;
            float hs = hsq[m];
            u64 bestk = 0ull;
#pragma unroll
            for (int fn = 0; fn < 2; ++fn) {
                if (okn[fn]) {
                    float dot1 = acc1[fm][fn][r] + acc1x[fm][fn][r] * inv;
                    float dot2 = acc2[fm][fn][r] + acc2x[fm][fn][r] * inv;
                    float sc = (dot1 + bev[fn])
                             - 0.5f * sqrtf(fmaxf(hs + osv[fn] - 2.0f * dot2, 0.0f));
                    out[(size_t)m * NOPS + nn[fn]] = sc;
                    unsigned int u = __float_as_uint(sc);
                    unsigned int mono = (u & 0x80000000u) ? ~u : (u | 0x80000000u);
                    u64 key = ((u64)mono << 32) | (u64)(0xFFFFFFFFu - (unsigned)nn[fn]);
                    if (key > bestk) bestk = key;
                }
            }
#pragma unroll
            for (int off = 1; off < 16; off <<= 1) {
                u64 ok = __shfl_xor(bestk, off);
                if (ok > bestk) bestk = ok;
            }
            if ((lane & 15) == 0) atomicMax(amax + m, bestk);
        }
    }
}

// ---------------- triple-split MFMA proj (K-chunk 64, + traj write) -------------------
// LDS: sA [third 3][kslot 2][32][32] = 12 KiB; sB [third 3][kslot 2][64][32] = 24 KiB.
__global__ __launch_bounds__(256) void proj_mfma3(
    const f16* __restrict__ H0, const f16* __restrict__ H1, const f16* __restrict__ H2,
    const f16* __restrict__ E0, const f16* __restrict__ E1, const f16* __restrict__ E2,
    const u64* __restrict__ amax,
    const f16* __restrict__ W0, const f16* __restrict__ W1, const f16* __restrict__ W2,
    const float* __restrict__ bp,
    f16* __restrict__ X0, f16* __restrict__ X1, f16* __restrict__ X2,
    float* __restrict__ traj) {
    __shared__ __align__(16) f16 sA[3 * 2 * 32 * 32];
    __shared__ __align__(16) f16 sB[3 * 2 * 64 * 32];
    int tid = threadIdx.x;
    int lane = tid & 63;
    int wave = tid >> 6;
    int mw = wave & 1;
    int nh = wave >> 1;
    int n0 = blockIdx.x * 64;
    int m0 = blockIdx.y * 32;

    if (blockIdx.x == 0 && tid < 32) {
        int row = m0 + tid;
        unsigned int selv = 0xFFFFFFFFu - (unsigned int)(amax[row] & 0xFFFFFFFFull);
        traj[row] = (float)selv;
    }

    f32x4 acc[2], accx[2], accy[2];
#pragma unroll
    for (int j = 0; j < 2; ++j) {
        acc[j] = (f32x4){0.f, 0.f, 0.f, 0.f};
        accx[j] = (f32x4){0.f, 0.f, 0.f, 0.f};
        accy[j] = (f32x4){0.f, 0.f, 0.f, 0.f};
    }

    for (int k0 = 0; k0 < 512; k0 += 64) {
        // stage A: 3 x 2 x 32 x 4 = 768 float4 (3 passes)
#pragma unroll
        for (int it = 0; it < 3; ++it) {
            int idx = tid + 256 * it;
            int third = idx >> 8;
            int rem = idx & 255;
            int kslot = rem >> 7;
            int within = rem & 127;
            int row = within >> 2, slot = within & 3;
            int gr = m0 + row;
            int keff = k0 + kslot * 32;
            const f16* src;
            if (keff < 256) {
                const f16* base = (third == 0 ? H0 : third == 1 ? H1 : H2);
                src = base + (size_t)gr * 256 + keff + slot * 8;
            } else {
                unsigned int selv = 0xFFFFFFFFu - (unsigned int)(amax[gr] & 0xFFFFFFFFull);
                const f16* base = (third == 0 ? E0 : third == 1 ? E1 : E2);
                src = base + (size_t)selv * 256 + (keff - 256) + slot * 8;
            }
            *(float4*)&sA[third * 2048 + kslot * 1024 + row * 32 + SWZ(row, slot) * 8] =
                *(const float4*)src;
        }
        // stage B: 3 x 2 x 64 x 4 = 1536 float4 (6 passes)
#pragma unroll
        for (int it = 0; it < 6; ++it) {
            int idx = tid + 256 * it;
            int third = idx >> 9;
            int rem = idx & 511;
            int kslot = rem >> 8;
            int within = rem & 255;
            int row = within >> 2, slot = within & 3;
            const f16* src = (third == 0 ? W0 : third == 1 ? W1 : W2)
                             + (size_t)(n0 + row) * 512 + k0 + kslot * 32 + slot * 8;
            *(float4*)&sB[third * 4096 + kslot * 2048 + row * 32 + SWZ(row, slot) * 8] =
                *(const float4*)src;
        }
        __syncthreads();
#pragma unroll
        for (int kslot = 0; kslot < 2; ++kslot) {
            int ar = mw * 16 + (lane & 15);
            int asl = SWZ(ar, lane >> 4);
            f16x8 a0 = *(const f16x8*)&sA[kslot * 1024 + ar * 32 + asl * 8];
            f16x8 a1 = *(const f16x8*)&sA[2048 + kslot * 1024 + ar * 32 + asl * 8];
            f16x8 a2 = *(const f16x8*)&sA[4096 + kslot * 1024 + ar * 32 + asl * 8];
#pragma unroll
            for (int j = 0; j < 2; ++j) {
                int brr = (nh * 2 + j) * 16 + (lane & 15);
                int bsl = SWZ(brr, lane >> 4);
                f16x8 b0 = *(const f16x8*)&sB[kslot * 2048 + brr * 32 + bsl * 8];
                f16x8 b1 = *(const f16x8*)&sB[4096 + kslot * 2048 + brr * 32 + bsl * 8];
                f16x8 b2 = *(const f16x8*)&sB[8192 + kslot * 2048 + brr * 32 + bsl * 8];
                acc[j]  = __builtin_amdgcn_mfma_f32_16x16x32_f16(a0, b0, acc[j], 0, 0, 0);
                accx[j] = __builtin_amdgcn_mfma_f32_16x16x32_f16(a0, b1, accx[j], 0, 0, 0);
                accx[j] = __builtin_amdgcn_mfma_f32_16x16x32_f16(a1, b0, accx[j], 0, 0, 0);
                accy[j] = __builtin_amdgcn_mfma_f32_16x16x32_f16(a0, b2, accy[j], 0, 0, 0);
                accy[j] = __builtin_amdgcn_mfma_f32_16x16x32_f16(a1, b1, accy[j], 0, 0, 0);
                accy[j] = __builtin_amdgcn_mfma_f32_16x16x32_f16(a2, b0, accy[j], 0, 0, 0);
            }
        }
        __syncthreads();
    }

#pragma unroll
    for (int j = 0; j < 2; ++j) {
        int n = n0 + (nh * 2 + j) * 16 + (lane & 15);
        float bv = bp[n];
#pragma unroll
        for (int r = 0; r < 4; ++r) {
            int m = m0 + mw * 16 + (lane >> 4) * 4 + r;
            float o = acc[j][r] + accx[j][r] * S1 + accy[j][r] * S2 + bv;
            f16 q0, q1, q2;
            split3(o, q0, q1, q2);
            X0[(size_t)m * 320 + n] = q0;
            X1[(size_t)m * 320 + n] = q1;
            X2[(size_t)m * 320 + n] = q2;
        }
    }
}

extern "C" void kernel_launch(void* const* d_in, const int* in_sizes, int n_in,
                              void* d_out, int out_size, void* d_ws, size_t ws_size,
                              hipStream_t stream) {
    const float* geo      = (const float*)d_in[0];
    const float* sem      = (const float*)d_in[1];
    const float* w_ih0    = (const float*)d_in[2];
    const float* w_hh0    = (const float*)d_in[3];
    const float* b_ih0    = (const float*)d_in[4];
    const float* b_hh0    = (const float*)d_in[5];
    const float* w_ih1    = (const float*)d_in[6];
    const float* w_hh1    = (const float*)d_in[7];
    const float* b_ih1    = (const float*)d_in[8];
    const float* b_hh1    = (const float*)d_in[9];
    const float* w_energy = (const float*)d_in[10];
    const float* b_energy = (const float*)d_in[11];
    const float* w_proj   = (const float*)d_in[12];
    const float* b_proj   = (const float*)d_in[13];
    const float* w_op     = (const float*)d_in[14];
    const float* op_emb   = (const float*)d_in[15];

    char* p = (char*)d_ws;
    auto alloc = [&](size_t bytes) { char* q = p; p += (bytes + 255) & ~255ULL; return q; };
    float* opp   = (float*)alloc((size_t)NOPS * 256 * 4);
    float* oppsq = (float*)alloc((size_t)NOPS * 4);
    float* hsq   = (float*)alloc((size_t)B * 4);
    u64*   amax  = (u64*)  alloc((size_t)B * 8);
    float *h0f[2], *h1f[2];
    f16 *h0c[2][3], *h1c[2][3];
    for (int i = 0; i < 2; ++i) {
        h0f[i] = (float*)alloc((size_t)B * H * 4);
        h1f[i] = (float*)alloc((size_t)B * H * 4);
        for (int j = 0; j < 3; ++j) {
            h0c[i][j] = (f16*)alloc((size_t)B * H * 2);
            h1c[i][j] = (f16*)alloc((size_t)B * H * 2);
        }
    }
    f16* x0 = (f16*)alloc((size_t)B * INDIM * 2);
    f16* x1 = (f16*)alloc((size_t)B * INDIM * 2);
    f16* x2 = (f16*)alloc((size_t)B * INDIM * 2);
    f16 *wi0[3], *wh0[3], *wi1[3], *wh1[3], *wp[3], *emb[3];
    for (int i = 0; i < 3; ++i) {
        wi0[i] = (f16*)alloc((size_t)768 * 320 * 2);
        wh0[i] = (f16*)alloc((size_t)768 * 256 * 2);
        wi1[i] = (f16*)alloc((size_t)768 * 256 * 2);
        wh1[i] = (f16*)alloc((size_t)768 * 256 * 2);
        wp[i]  = (f16*)alloc((size_t)320 * 512 * 2);
        emb[i] = (f16*)alloc((size_t)NOPS * 256 * 2);
    }
    f16* weh = (f16*)alloc((size_t)NOPS * 256 * 2);
    f16* wel = (f16*)alloc((size_t)NOPS * 256 * 2);
    f16* oph = (f16*)alloc((size_t)NOPS * 256 * 2);
    f16* opl = (f16*)alloc((size_t)NOPS * 256 * 2);

    float* out    = (float*)d_out;
    float* traj   = out;
    float* scores = out + (size_t)STEPS * B;

    init_kernel<<<dim3((B * INDIM + 255) / 256), dim3(256), 0, stream>>>(
        geo, sem, x0, x1, x2, h0f[0], h1f[0],
        h0c[0][0], h0c[0][1], h0c[0][2], h1c[0][0], h1c[0][1], h1c[0][2],
        hsq, amax);
    gemm_tn<<<dim3(256 / BN, (NOPS + BM - 1) / BM), dim3(256), 0, stream>>>(
        op_emb, w_op, nullptr, opp, NOPS, 256, 256);
    cvt3_rows<<<dim3(192), dim3(256), 0, stream>>>(w_ih0, 768, 320, wi0[0], wi0[1], wi0[2]);
    cvt3_rows<<<dim3(192), dim3(256), 0, stream>>>(w_hh0, 768, 256, wh0[0], wh0[1], wh0[2]);
    cvt3_rows<<<dim3(192), dim3(256), 0, stream>>>(w_ih1, 768, 256, wi1[0], wi1[1], wi1[2]);
    cvt3_rows<<<dim3(192), dim3(256), 0, stream>>>(w_hh1, 768, 256, wh1[0], wh1[1], wh1[2]);
    cvt3_rows<<<dim3(80), dim3(256), 0, stream>>>(w_proj, 320, 512, wp[0], wp[1], wp[2]);
    cvt3_rows<<<dim3((NOPS + 3) / 4), dim3(256), 0, stream>>>(op_emb, NOPS, 256, emb[0], emb[1], emb[2]);
    cvt_rows<<<dim3((NOPS + 3) / 4), dim3(256), 0, stream>>>(w_energy, NOPS, 256, weh, wel, nullptr);
    cvt_rows<<<dim3((NOPS + 3) / 4), dim3(256), 0, stream>>>(opp, NOPS, 256, oph, opl, oppsq);

    for (int t = 0; t < STEPS; ++t) {
        int pi = t & 1, po = pi ^ 1;

        // gru0: also zeroes hsq for this step (consumed by gru1's atomics)
        gru_mfma3<<<dim3(H / 32, B / 64), dim3(512), 0, stream>>>(
            x0, x1, x2, INDIM, wi0[0], wi0[1], wi0[2],
            h0c[pi][0], h0c[pi][1], h0c[pi][2], wh0[0], wh0[1], wh0[2],
            b_ih0, b_hh0, h0f[pi], h0f[po], h0c[po][0], h0c[po][1], h0c[po][2],
            hsq, nullptr, nullptr);
        // gru1: accumulates hsq, zeroes amax for this step's scores
        gru_mfma3<<<dim3(H / 32, B / 64), dim3(512), 0, stream>>>(
            h0c[po][0], h0c[po][1], h0c[po][2], 256, wi1[0], wi1[1], wi1[2],
            h1c[pi][0], h1c[pi][1], h1c[pi][2], wh1[0], wh1[1], wh1[2],
            b_ih1, b_hh1, h1f[pi], h1f[po], h1c[po][0], h1c[po][1], h1c[po][2],
            nullptr, hsq, amax);

        scores_mfma<<<dim3((NOPS + 63) / 64, B / 128), dim3(256), 0, stream>>>(
            h1c[po][0], h1c[po][1], weh, wel, oph, opl, hsq, b_energy, oppsq,
            scores + (size_t)t * B * NOPS, amax);
        proj_mfma3<<<dim3(320 / 64, B / 32), dim3(256), 0, stream>>>(
            h1c[po][0], h1c[po][1], h1c[po][2], emb[0], emb[1], emb[2], amax,
            wp[0], wp[1], wp[2], b_proj, x0, x1, x2, traj + (size_t)t * B);
    }
}

// Round 7
// 2273.119 us; speedup vs baseline: 5.3332x; 1.1106x over previous
//
#include <hip/hip_runtime.h>
#include <math.h>

#define B 2048
#define H 256
#define INDIM 320
#define NOPS 1883
#define STEPS 20

typedef _Float16 f16;
typedef _Float16 f16x4 __attribute__((ext_vector_type(4)));
typedef _Float16 f16x8 __attribute__((ext_vector_type(8)));
typedef float f32x4 __attribute__((ext_vector_type(4)));
typedef unsigned long long u64;

// XOR swizzle: 4 16B-slots per 64B (32-f16) row; bijective involution per row.
#define SWZ(r, s) ((s) ^ ((r) & 3) ^ (((r) >> 2) & 1))

#define S1 (1.0f / 1024.0f)
#define S2 (1.0f / 1048576.0f)

__device__ __forceinline__ void split3(float f, f16& c0, f16& c1, f16& c2) {
    c0 = (f16)f;
    float r1 = f - (float)c0;
    c1 = (f16)(r1 * 1024.0f);
    float r2 = r1 - (float)c1 * S1;
    c2 = (f16)(r2 * 1048576.0f);
}

// ---------------- init: x = concat(geo,sem) triple-split; zero h state + reductions ---
__global__ __launch_bounds__(256) void init_kernel(const float* __restrict__ geo,
                                                   const float* __restrict__ sem,
                                                   f16* __restrict__ x0, f16* __restrict__ x1,
                                                   f16* __restrict__ x2,
                                                   float* __restrict__ h0f, float* __restrict__ h1f,
                                                   f16* __restrict__ h0c0, f16* __restrict__ h0c1,
                                                   f16* __restrict__ h0c2,
                                                   f16* __restrict__ h1c0, f16* __restrict__ h1c1,
                                                   f16* __restrict__ h1c2,
                                                   float* __restrict__ hsq, u64* __restrict__ amax) {
    int i = blockIdx.x * blockDim.x + threadIdx.x;
    if (i < B * INDIM) {
        int b = i / INDIM, c = i % INDIM;
        float f = (c < 256) ? geo[b * 256 + c] : sem[b * 64 + (c - 256)];
        f16 a, bb, cc;
        split3(f, a, bb, cc);
        x0[i] = a; x1[i] = bb; x2[i] = cc;
    }
    if (i < B * H) {
        h0f[i] = 0.0f; h1f[i] = 0.0f;
        h0c0[i] = (f16)0.0f; h0c1[i] = (f16)0.0f; h0c2[i] = (f16)0.0f;
        h1c0[i] = (f16)0.0f; h1c1[i] = (f16)0.0f; h1c2[i] = (f16)0.0f;
    }
    if (i < B) { hsq[i] = 0.0f; amax[i] = 0ull; }
}

// ---------------- generic tiled GEMM C = A * B^T (opp precompute) ----------------
#define BM 64
#define BN 64
#define BK 16
__global__ __launch_bounds__(256) void gemm_tn(const float* __restrict__ A,
                                               const float* __restrict__ Bm,
                                               const float* __restrict__ bias,
                                               float* __restrict__ C,
                                               int M, int N, int K) {
    __shared__ float As[BK][BM];
    __shared__ float Bs[BK][BN];
    int tid = threadIdx.x;
    int bm0 = blockIdx.y * BM;
    int bn0 = blockIdx.x * BN;
    int tx = tid & 15, ty = tid >> 4;
    int lr = tid >> 2;
    int lk = (tid & 3) << 2;

    float acc[4][4];
#pragma unroll
    for (int i = 0; i < 4; ++i)
#pragma unroll
        for (int j = 0; j < 4; ++j) acc[i][j] = 0.0f;

    for (int k0 = 0; k0 < K; k0 += BK) {
        {
            int gr = bm0 + lr;
            float4 v = make_float4(0.f, 0.f, 0.f, 0.f);
            if (gr < M) v = *(const float4*)(A + (size_t)gr * K + k0 + lk);
            As[lk + 0][lr] = v.x; As[lk + 1][lr] = v.y;
            As[lk + 2][lr] = v.z; As[lk + 3][lr] = v.w;
        }
        {
            int gn = bn0 + lr;
            float4 v = make_float4(0.f, 0.f, 0.f, 0.f);
            if (gn < N) v = *(const float4*)(Bm + (size_t)gn * K + k0 + lk);
            Bs[lk + 0][lr] = v.x; Bs[lk + 1][lr] = v.y;
            Bs[lk + 2][lr] = v.z; Bs[lk + 3][lr] = v.w;
        }
        __syncthreads();
#pragma unroll
        for (int k = 0; k < BK; ++k) {
            float a[4], b[4];
#pragma unroll
            for (int i = 0; i < 4; ++i) a[i] = As[k][ty * 4 + i];
#pragma unroll
            for (int j = 0; j < 4; ++j) b[j] = Bs[k][tx * 4 + j];
#pragma unroll
            for (int i = 0; i < 4; ++i)
#pragma unroll
                for (int j = 0; j < 4; ++j) acc[i][j] = fmaf(a[i], b[j], acc[i][j]);
        }
        __syncthreads();
    }
#pragma unroll
    for (int i = 0; i < 4; ++i) {
        int gr = bm0 + ty * 4 + i;
        if (gr >= M) continue;
#pragma unroll
        for (int j = 0; j < 4; ++j) {
            int gc = bn0 + tx * 4 + j;
            if (gc < N) C[(size_t)gr * N + gc] = acc[i][j] + (bias ? bias[gc] : 0.0f);
        }
    }
}

// ---------------- tiled GEMM C = A * B (A (M,K) rm, B (K,N) rm) — Wc precompute -------
__global__ __launch_bounds__(256) void gemm_nn(const float* __restrict__ A,
                                               const float* __restrict__ Bm,
                                               float* __restrict__ C,
                                               int M, int N, int K) {
    __shared__ float As[BK][BM];
    __shared__ float Bs[BK][BN];
    int tid = threadIdx.x;
    int bm0 = blockIdx.y * BM;
    int bn0 = blockIdx.x * BN;
    int tx = tid & 15, ty = tid >> 4;
    int lr = tid >> 2;
    int lk = (tid & 3) << 2;

    float acc[4][4];
#pragma unroll
    for (int i = 0; i < 4; ++i)
#pragma unroll
        for (int j = 0; j < 4; ++j) acc[i][j] = 0.0f;

    for (int k0 = 0; k0 < K; k0 += BK) {
        {
            int gr = bm0 + lr;
            float4 v = make_float4(0.f, 0.f, 0.f, 0.f);
            if (gr < M) v = *(const float4*)(A + (size_t)gr * K + k0 + lk);
            As[lk + 0][lr] = v.x; As[lk + 1][lr] = v.y;
            As[lk + 2][lr] = v.z; As[lk + 3][lr] = v.w;
        }
        {
            int kk = tid >> 4;          // 0..15
            int n4 = (tid & 15) << 2;   // 0..60
            float4 v = *(const float4*)(Bm + (size_t)(k0 + kk) * N + bn0 + n4);
            Bs[kk][n4 + 0] = v.x; Bs[kk][n4 + 1] = v.y;
            Bs[kk][n4 + 2] = v.z; Bs[kk][n4 + 3] = v.w;
        }
        __syncthreads();
#pragma unroll
        for (int k = 0; k < BK; ++k) {
            float a[4], b[4];
#pragma unroll
            for (int i = 0; i < 4; ++i) a[i] = As[k][ty * 4 + i];
#pragma unroll
            for (int j = 0; j < 4; ++j) b[j] = Bs[k][tx * 4 + j];
#pragma unroll
            for (int i = 0; i < 4; ++i)
#pragma unroll
                for (int j = 0; j < 4; ++j) acc[i][j] = fmaf(a[i], b[j], acc[i][j]);
        }
        __syncthreads();
    }
#pragma unroll
    for (int i = 0; i < 4; ++i) {
        int gr = bm0 + ty * 4 + i;
        if (gr >= M) continue;
#pragma unroll
        for (int j = 0; j < 4; ++j) {
            int gc = bn0 + tx * 4 + j;
            if (gc < N) C[(size_t)gr * N + gc] = acc[i][j];
        }
    }
}

// ---------------- bihc[g] = b_ih0[g] + dot(Wi0[g,:320], bp) ----------------
__global__ __launch_bounds__(256) void rowdot_bias(const float* __restrict__ A,
                                                   const float* __restrict__ v,
                                                   const float* __restrict__ b0,
                                                   float* __restrict__ outb) {
    int row = blockIdx.x * 4 + (threadIdx.x >> 6);
    int lane = threadIdx.x & 63;
    if (row >= 768) return;
    float s = 0.0f;
    for (int j = lane; j < 320; j += 64) s = fmaf(A[(size_t)row * 320 + j], v[j], s);
#pragma unroll
    for (int off = 32; off > 0; off >>= 1) s += __shfl_down(s, off);
    if (lane == 0) outb[row] = b0[row] + s;
}

// ---------------- fp32 -> fp16 hi/lo double split (lo x1024) + optional row sumsq -----
__global__ __launch_bounds__(256) void cvt_rows(const float* __restrict__ A, int rows, int cols,
                                                f16* __restrict__ hi, f16* __restrict__ lo,
                                                float* __restrict__ sq) {
    int row = blockIdx.x * 4 + (threadIdx.x >> 6);
    int lane = threadIdx.x & 63;
    if (row >= rows) return;
    const float* src = A + (size_t)row * cols;
    float s = 0.0f;
    for (int c0 = 0; c0 < cols; c0 += 256) {
        int idx = c0 + lane * 4;
        if (idx < cols) {
            float4 v = *(const float4*)(src + idx);
            float vv[4] = {v.x, v.y, v.z, v.w};
            f16x4 h, l;
#pragma unroll
            for (int j = 0; j < 4; ++j) {
                float f = vv[j];
                f16 hv = (f16)f;
                h[j] = hv;
                l[j] = (f16)((f - (float)hv) * 1024.0f);
                s = fmaf(f, f, s);
            }
            *(f16x4*)(hi + (size_t)row * cols + idx) = h;
            *(f16x4*)(lo + (size_t)row * cols + idx) = l;
        }
    }
    if (sq) {
#pragma unroll
        for (int off = 32; off > 0; off >>= 1) s += __shfl_down(s, off);
        if (lane == 0) sq[row] = s;
    }
}

// ---------------- fp32 -> fp16 triple split ----------------
__global__ __launch_bounds__(256) void cvt3_rows(const float* __restrict__ A, int rows, int cols,
                                                 f16* __restrict__ o0, f16* __restrict__ o1,
                                                 f16* __restrict__ o2) {
    int row = blockIdx.x * 4 + (threadIdx.x >> 6);
    int lane = threadIdx.x & 63;
    if (row >= rows) return;
    const float* src = A + (size_t)row * cols;
    for (int c0 = 0; c0 < cols; c0 += 256) {
        int idx = c0 + lane * 4;
        if (idx < cols) {
            float4 v = *(const float4*)(src + idx);
            float vv[4] = {v.x, v.y, v.z, v.w};
            f16x4 a, b, c;
#pragma unroll
            for (int j = 0; j < 4; ++j) {
                f16 p, q, r;
                split3(vv[j], p, q, r);
                a[j] = p; b[j] = q; c[j] = r;
            }
            *(f16x4*)(o0 + (size_t)row * cols + idx) = a;
            *(f16x4*)(o1 + (size_t)row * cols + idx) = b;
            *(f16x4*)(o2 + (size_t)row * cols + idx) = c;
        }
    }
}

// ---------------- triple-split MFMA GRU k-phase (M=64, 512 threads, K-chunk 64) -------
__device__ __forceinline__ void gru_phase3(
    const f16* __restrict__ A0, const f16* __restrict__ A1, const f16* __restrict__ A2,
    const f16* __restrict__ W0, const f16* __restrict__ W1, const f16* __restrict__ W2,
    int K, int m0, int c0, int tid, int lane, int mfrag, int hhalf,
    f32x4* acc, f32x4* accx, f32x4* accy, f16* sA, f16* sW) {
    for (int k0 = 0; k0 < K; k0 += 64) {
#pragma unroll
        for (int it = 0; it < 3; ++it) {
            int idx = tid + 512 * it;
            int third = idx >> 9;
            int rem = idx & 511;
            int kslot = rem >> 8;
            int within = rem & 255;
            int row = within >> 2, slot = within & 3;
            const f16* src = (third == 0 ? A0 : third == 1 ? A1 : A2)
                             + (size_t)(m0 + row) * K + k0 + kslot * 32 + slot * 8;
            *(float4*)&sA[third * 4096 + kslot * 2048 + row * 32 + SWZ(row, slot) * 8] =
                *(const float4*)src;
        }
#pragma unroll
        for (int it = 0; it < 5; ++it) {
            int idx = tid + 512 * it;
            if (idx < 2304) {
                int third = idx / 768;
                int rem = idx - third * 768;
                int kslot = rem / 384;
                int within = rem - kslot * 384;
                int row = within >> 2, slot = within & 3;
                int wr = ((row >> 5) << 8) + c0 + (row & 31);
                const f16* src = (third == 0 ? W0 : third == 1 ? W1 : W2)
                                 + (size_t)wr * K + k0 + kslot * 32 + slot * 8;
                *(float4*)&sW[third * 6144 + kslot * 3072 + row * 32 + SWZ(row, slot) * 8] =
                    *(const float4*)src;
            }
        }
        __syncthreads();
#pragma unroll
        for (int kslot = 0; kslot < 2; ++kslot) {
            int ar = mfrag * 16 + (lane & 15);
            int asl = SWZ(ar, lane >> 4);
            f16x8 a0 = *(const f16x8*)&sA[kslot * 2048 + ar * 32 + asl * 8];
            f16x8 a1 = *(const f16x8*)&sA[4096 + kslot * 2048 + ar * 32 + asl * 8];
            f16x8 a2 = *(const f16x8*)&sA[8192 + kslot * 2048 + ar * 32 + asl * 8];
#pragma unroll
            for (int g = 0; g < 3; ++g) {
                int br_ = g * 32 + hhalf * 16 + (lane & 15);
                int bsl = SWZ(br_, lane >> 4);
                f16x8 b0 = *(const f16x8*)&sW[kslot * 3072 + br_ * 32 + bsl * 8];
                f16x8 b1 = *(const f16x8*)&sW[6144 + kslot * 3072 + br_ * 32 + bsl * 8];
                f16x8 b2 = *(const f16x8*)&sW[12288 + kslot * 3072 + br_ * 32 + bsl * 8];
                acc[g]  = __builtin_amdgcn_mfma_f32_16x16x32_f16(a0, b0, acc[g], 0, 0, 0);
                accx[g] = __builtin_amdgcn_mfma_f32_16x16x32_f16(a0, b1, accx[g], 0, 0, 0);
                accx[g] = __builtin_amdgcn_mfma_f32_16x16x32_f16(a1, b0, accx[g], 0, 0, 0);
                accy[g] = __builtin_amdgcn_mfma_f32_16x16x32_f16(a0, b2, accy[g], 0, 0, 0);
                accy[g] = __builtin_amdgcn_mfma_f32_16x16x32_f16(a1, b1, accy[g], 0, 0, 0);
                accy[g] = __builtin_amdgcn_mfma_f32_16x16x32_f16(a2, b0, accy[g], 0, 0, 0);
            }
        }
        __syncthreads();
    }
}

// A-operand = concat(H1[256], emb[sel][256]); W stride 512.
__device__ __forceinline__ void gru_phase3_f(
    const f16* __restrict__ H10, const f16* __restrict__ H11, const f16* __restrict__ H12,
    const f16* __restrict__ E0, const f16* __restrict__ E1, const f16* __restrict__ E2,
    const unsigned* __restrict__ sSel,
    const f16* __restrict__ W0, const f16* __restrict__ W1, const f16* __restrict__ W2,
    int m0, int c0, int tid, int lane, int mfrag, int hhalf,
    f32x4* acc, f32x4* accx, f32x4* accy, f16* sA, f16* sW) {
    for (int k0 = 0; k0 < 512; k0 += 64) {
#pragma unroll
        for (int it = 0; it < 3; ++it) {
            int idx = tid + 512 * it;
            int third = idx >> 9;
            int rem = idx & 511;
            int kslot = rem >> 8;
            int within = rem & 255;
            int row = within >> 2, slot = within & 3;
            int keff = k0 + kslot * 32;
            const f16* src;
            if (keff < 256) {
                const f16* base = (third == 0 ? H10 : third == 1 ? H11 : H12);
                src = base + (size_t)(m0 + row) * 256 + keff + slot * 8;
            } else {
                const f16* base = (third == 0 ? E0 : third == 1 ? E1 : E2);
                src = base + (size_t)sSel[row] * 256 + (keff - 256) + slot * 8;
            }
            *(float4*)&sA[third * 4096 + kslot * 2048 + row * 32 + SWZ(row, slot) * 8] =
                *(const float4*)src;
        }
#pragma unroll
        for (int it = 0; it < 5; ++it) {
            int idx = tid + 512 * it;
            if (idx < 2304) {
                int third = idx / 768;
                int rem = idx - third * 768;
                int kslot = rem / 384;
                int within = rem - kslot * 384;
                int row = within >> 2, slot = within & 3;
                int wr = ((row >> 5) << 8) + c0 + (row & 31);
                const f16* src = (third == 0 ? W0 : third == 1 ? W1 : W2)
                                 + (size_t)wr * 512 + k0 + kslot * 32 + slot * 8;
                *(float4*)&sW[third * 6144 + kslot * 3072 + row * 32 + SWZ(row, slot) * 8] =
                    *(const float4*)src;
            }
        }
        __syncthreads();
#pragma unroll
        for (int kslot = 0; kslot < 2; ++kslot) {
            int ar = mfrag * 16 + (lane & 15);
            int asl = SWZ(ar, lane >> 4);
            f16x8 a0 = *(const f16x8*)&sA[kslot * 2048 + ar * 32 + asl * 8];
            f16x8 a1 = *(const f16x8*)&sA[4096 + kslot * 2048 + ar * 32 + asl * 8];
            f16x8 a2 = *(const f16x8*)&sA[8192 + kslot * 2048 + ar * 32 + asl * 8];
#pragma unroll
            for (int g = 0; g < 3; ++g) {
                int br_ = g * 32 + hhalf * 16 + (lane & 15);
                int bsl = SWZ(br_, lane >> 4);
                f16x8 b0 = *(const f16x8*)&sW[kslot * 3072 + br_ * 32 + bsl * 8];
                f16x8 b1 = *(const f16x8*)&sW[6144 + kslot * 3072 + br_ * 32 + bsl * 8];
                f16x8 b2 = *(const f16x8*)&sW[12288 + kslot * 3072 + br_ * 32 + bsl * 8];
                acc[g]  = __builtin_amdgcn_mfma_f32_16x16x32_f16(a0, b0, acc[g], 0, 0, 0);
                accx[g] = __builtin_amdgcn_mfma_f32_16x16x32_f16(a0, b1, accx[g], 0, 0, 0);
                accx[g] = __builtin_amdgcn_mfma_f32_16x16x32_f16(a1, b0, accx[g], 0, 0, 0);
                accy[g] = __builtin_amdgcn_mfma_f32_16x16x32_f16(a0, b2, accy[g], 0, 0, 0);
                accy[g] = __builtin_amdgcn_mfma_f32_16x16x32_f16(a1, b1, accy[g], 0, 0, 0);
                accy[g] = __builtin_amdgcn_mfma_f32_16x16x32_f16(a2, b0, accy[g], 0, 0, 0);
            }
        }
        __syncthreads();
    }
}

// ---------------- GRU epilogue (shared) ----------------
__device__ __forceinline__ void gru_epilogue(
    f32x4* acc, f32x4* accx, f32x4* accy, float gi[3][4],
    const float* bih, const float* bhh,
    const float* Hprevf, float* Hnewf,
    f16* O0, f16* O1, f16* O2, float* hsq_acc,
    int m0, int c0, int lane, int mfrag, int hhalf) {
    int c = c0 + hhalf * 16 + (lane & 15);
    float br = bih[c] + bhh[c];
    float bz = bih[256 + c] + bhh[256 + c];
    float bni = bih[512 + c];
    float bnh = bhh[512 + c];
#pragma unroll
    for (int r = 0; r < 4; ++r) {
        int row = m0 + mfrag * 16 + (lane >> 4) * 4 + r;
        float gh_r = acc[0][r] + accx[0][r] * S1 + accy[0][r] * S2;
        float gh_z = acc[1][r] + accx[1][r] * S1 + accy[1][r] * S2;
        float gh_n = acc[2][r] + accx[2][r] * S1 + accy[2][r] * S2;
        float rg = 1.0f / (1.0f + expf(-(gi[0][r] + gh_r + br)));
        float zg = 1.0f / (1.0f + expf(-(gi[1][r] + gh_z + bz)));
        float ng = tanhf(gi[2][r] + bni + rg * (gh_n + bnh));
        float hp = Hprevf[(size_t)row * 256 + c];
        float o = (1.0f - zg) * ng + zg * hp;
        Hnewf[(size_t)row * 256 + c] = o;
        f16 q0, q1, q2;
        split3(o, q0, q1, q2);
        O0[(size_t)row * 256 + c] = q0;
        O1[(size_t)row * 256 + c] = q1;
        O2[(size_t)row * 256 + c] = q2;
        if (hsq_acc) {
            float sq = o * o;
#pragma unroll
            for (int off = 1; off < 16; off <<= 1) sq += __shfl_xor(sq, off);
            if ((lane & 15) == 0) atomicAdd(hsq_acc + row, sq);
        }
    }
}

// ---------------- GRU layer (generic A, used for t=0 gru0 and all gru1) ---------------
__global__ __launch_bounds__(512) void gru_mfma3(
    const f16* __restrict__ A0, const f16* __restrict__ A1, const f16* __restrict__ A2, int K1,
    const f16* __restrict__ Wi0, const f16* __restrict__ Wi1, const f16* __restrict__ Wi2,
    const f16* __restrict__ P0, const f16* __restrict__ P1, const f16* __restrict__ P2,
    const f16* __restrict__ Wh0, const f16* __restrict__ Wh1, const f16* __restrict__ Wh2,
    const float* __restrict__ bih, const float* __restrict__ bhh,
    const float* __restrict__ Hprevf,
    float* __restrict__ Hnewf,
    f16* __restrict__ O0, f16* __restrict__ O1, f16* __restrict__ O2,
    float* __restrict__ hsq_zero, float* __restrict__ hsq_acc,
    u64* __restrict__ amax_zero) {
    __shared__ __align__(16) f16 sA[3 * 2 * 64 * 32];
    __shared__ __align__(16) f16 sW[3 * 2 * 96 * 32];
    int tid = threadIdx.x;
    int lane = tid & 63;
    int wave = tid >> 6;
    int mfrag = wave & 3;
    int hhalf = wave >> 2;
    int c0 = blockIdx.x * 32;
    int m0 = blockIdx.y * 64;

    if (hsq_zero && blockIdx.x == 0 && tid < 64) hsq_zero[m0 + tid] = 0.0f;
    if (amax_zero && blockIdx.x == 0 && tid < 64) amax_zero[m0 + tid] = 0ull;

    f32x4 acc[3], accx[3], accy[3];
#pragma unroll
    for (int g = 0; g < 3; ++g) {
        acc[g] = (f32x4){0.f, 0.f, 0.f, 0.f};
        accx[g] = (f32x4){0.f, 0.f, 0.f, 0.f};
        accy[g] = (f32x4){0.f, 0.f, 0.f, 0.f};
    }

    gru_phase3(A0, A1, A2, Wi0, Wi1, Wi2, K1, m0, c0, tid, lane, mfrag, hhalf,
               acc, accx, accy, sA, sW);

    float gi[3][4];
#pragma unroll
    for (int g = 0; g < 3; ++g)
#pragma unroll
        for (int r = 0; r < 4; ++r) {
            gi[g][r] = acc[g][r] + accx[g][r] * S1 + accy[g][r] * S2;
            acc[g][r] = 0.f; accx[g][r] = 0.f; accy[g][r] = 0.f;
        }

    gru_phase3(P0, P1, P2, Wh0, Wh1, Wh2, 256, m0, c0, tid, lane, mfrag, hhalf,
               acc, accx, accy, sA, sW);

    gru_epilogue(acc, accx, accy, gi, bih, bhh, Hprevf, Hnewf, O0, O1, O2, hsq_acc,
                 m0, c0, lane, mfrag, hhalf);
}

// ---------------- folded GRU0 (t>=1): A = [h1_prev, emb[sel]] w/ Wc; writes traj -----
__global__ __launch_bounds__(512) void gru_mfma3_f(
    const f16* __restrict__ H10, const f16* __restrict__ H11, const f16* __restrict__ H12,
    const f16* __restrict__ E0, const f16* __restrict__ E1, const f16* __restrict__ E2,
    const u64* __restrict__ amax,
    const f16* __restrict__ Wc0, const f16* __restrict__ Wc1, const f16* __restrict__ Wc2,
    const f16* __restrict__ P0, const f16* __restrict__ P1, const f16* __restrict__ P2,
    const f16* __restrict__ Wh0, const f16* __restrict__ Wh1, const f16* __restrict__ Wh2,
    const float* __restrict__ bihc, const float* __restrict__ bhh,
    const float* __restrict__ Hprevf,
    float* __restrict__ Hnewf,
    f16* __restrict__ O0, f16* __restrict__ O1, f16* __restrict__ O2,
    float* __restrict__ hsq_zero, float* __restrict__ traj_prev) {
    __shared__ __align__(16) f16 sA[3 * 2 * 64 * 32];
    __shared__ __align__(16) f16 sW[3 * 2 * 96 * 32];
    __shared__ unsigned sSel[64];
    int tid = threadIdx.x;
    int lane = tid & 63;
    int wave = tid >> 6;
    int mfrag = wave & 3;
    int hhalf = wave >> 2;
    int c0 = blockIdx.x * 32;
    int m0 = blockIdx.y * 64;

    if (tid < 64) {
        unsigned selv = 0xFFFFFFFFu - (unsigned)(amax[m0 + tid] & 0xFFFFFFFFull);
        sSel[tid] = selv;
        if (blockIdx.x == 0) {
            traj_prev[m0 + tid] = (float)selv;
            if (hsq_zero) hsq_zero[m0 + tid] = 0.0f;
        }
    }
    __syncthreads();

    f32x4 acc[3], accx[3], accy[3];
#pragma unroll
    for (int g = 0; g < 3; ++g) {
        acc[g] = (f32x4){0.f, 0.f, 0.f, 0.f};
        accx[g] = (f32x4){0.f, 0.f, 0.f, 0.f};
        accy[g] = (f32x4){0.f, 0.f, 0.f, 0.f};
    }

    gru_phase3_f(H10, H11, H12, E0, E1, E2, sSel, Wc0, Wc1, Wc2,
                 m0, c0, tid, lane, mfrag, hhalf, acc, accx, accy, sA, sW);

    float gi[3][4];
#pragma unroll
    for (int g = 0; g < 3; ++g)
#pragma unroll
        for (int r = 0; r < 4; ++r) {
            gi[g][r] = acc[g][r] + accx[g][r] * S1 + accy[g][r] * S2;
            acc[g][r] = 0.f; accx[g][r] = 0.f; accy[g][r] = 0.f;
        }

    gru_phase3(P0, P1, P2, Wh0, Wh1, Wh2, 256, m0, c0, tid, lane, mfrag, hhalf,
               acc, accx, accy, sA, sW);

    gru_epilogue(acc, accx, accy, gi, bihc, bhh, Hprevf, Hnewf, O0, O1, O2, nullptr,
                 m0, c0, lane, mfrag, hhalf);
}

// ---------------- MFMA split-fp16 scores + fused argmax (K-chunk 64) ------------------
__global__ __launch_bounds__(256, 2) void scores_mfma(
    const f16* __restrict__ Ahh, const f16* __restrict__ All,
    const f16* __restrict__ W1h, const f16* __restrict__ W1l,
    const f16* __restrict__ W2h, const f16* __restrict__ W2l,
    const float* __restrict__ hsq, const float* __restrict__ be,
    const float* __restrict__ osq, float* __restrict__ out,
    u64* __restrict__ amax) {
    __shared__ __align__(16) f16 sA[2 * 2 * 128 * 32];
    __shared__ __align__(16) f16 sB[4 * 2 * 64 * 32];
    int tid = threadIdx.x;
    int lane = tid & 63;
    int wave = tid >> 6;
    int wm = wave >> 1;
    int wn = wave & 1;
    int n0 = blockIdx.x * 64;
    int m0 = blockIdx.y * 128;

    f32x4 acc1[4][2], acc1x[4][2], acc2[4][2], acc2x[4][2];
#pragma unroll
    for (int i = 0; i < 4; ++i)
#pragma unroll
        for (int j = 0; j < 2; ++j) {
            acc1[i][j] = (f32x4){0.f, 0.f, 0.f, 0.f};
            acc1x[i][j] = (f32x4){0.f, 0.f, 0.f, 0.f};
            acc2[i][j] = (f32x4){0.f, 0.f, 0.f, 0.f};
            acc2x[i][j] = (f32x4){0.f, 0.f, 0.f, 0.f};
        }

    for (int k0 = 0; k0 < 256; k0 += 64) {
#pragma unroll
        for (int it = 0; it < 8; ++it) {
            int idx = tid + 256 * it;
            int half = idx >> 10;
            int rem = idx & 1023;
            int kslot = rem >> 9;
            int within = rem & 511;
            int r = within >> 2, slt = within & 3;
            const f16* src = (half ? All : Ahh)
                             + (size_t)(m0 + r) * 256 + k0 + kslot * 32 + slt * 8;
            *(float4*)&sA[half * 8192 + kslot * 4096 + r * 32 + SWZ(r, slt) * 8] =
                *(const float4*)src;
        }
#pragma unroll
        for (int it = 0; it < 8; ++it) {
            int idx = tid + 256 * it;
            int arr = idx >> 9;
            int rem = idx & 511;
            int kslot = rem >> 8;
            int within = rem & 255;
            int r = within >> 2, slt = within & 3;
            const f16* src = (arr == 0) ? W1h : (arr == 1) ? W1l : (arr == 2) ? W2h : W2l;
            int gn = n0 + r;
            float4 v = make_float4(0.f, 0.f, 0.f, 0.f);
            if (gn < NOPS) v = *(const float4*)(src + (size_t)gn * 256 + k0 + kslot * 32 + slt * 8);
            *(float4*)&sB[arr * 4096 + kslot * 2048 + r * 32 + SWZ(r, slt) * 8] = v;
        }
        __syncthreads();

#pragma unroll
        for (int kslot = 0; kslot < 2; ++kslot) {
            f16x8 ah[4], al[4];
#pragma unroll
            for (int fm = 0; fm < 4; ++fm) {
                int r = wm * 64 + fm * 16 + (lane & 15);
                int sl = SWZ(r, lane >> 4);
                ah[fm] = *(const f16x8*)&sA[kslot * 4096 + r * 32 + sl * 8];
                al[fm] = *(const f16x8*)&sA[8192 + kslot * 4096 + r * 32 + sl * 8];
            }
#pragma unroll
            for (int fn = 0; fn < 2; ++fn) {
                int r = wn * 32 + fn * 16 + (lane & 15);
                int sl = SWZ(r, lane >> 4);
                f16x8 b1h = *(const f16x8*)&sB[kslot * 2048 + r * 32 + sl * 8];
                f16x8 b1l = *(const f16x8*)&sB[4096 + kslot * 2048 + r * 32 + sl * 8];
                f16x8 b2h = *(const f16x8*)&sB[8192 + kslot * 2048 + r * 32 + sl * 8];
                f16x8 b2l = *(const f16x8*)&sB[12288 + kslot * 2048 + r * 32 + sl * 8];
#pragma unroll
                for (int fm = 0; fm < 4; ++fm) {
                    acc1[fm][fn]  = __builtin_amdgcn_mfma_f32_16x16x32_f16(ah[fm], b1h, acc1[fm][fn], 0, 0, 0);
                    acc1x[fm][fn] = __builtin_amdgcn_mfma_f32_16x16x32_f16(al[fm], b1h, acc1x[fm][fn], 0, 0, 0);
                    acc1x[fm][fn] = __builtin_amdgcn_mfma_f32_16x16x32_f16(ah[fm], b1l, acc1x[fm][fn], 0, 0, 0);
                    acc2[fm][fn]  = __builtin_amdgcn_mfma_f32_16x16x32_f16(ah[fm], b2h, acc2[fm][fn], 0, 0, 0);
                    acc2x[fm][fn] = __builtin_amdgcn_mfma_f32_16x16x32_f16(al[fm], b2h, acc2x[fm][fn], 0, 0, 0);
                    acc2x[fm][fn] = __builtin_amdgcn_mfma_f32_16x16x32_f16(ah[fm], b2l, acc2x[fm][fn], 0, 0, 0);
                }
            }
        }
        __syncthreads();
    }

    const float inv = 1.0f / 1024.0f;
    int nn[2]; float bev[2], osv[2]; bool okn[2];
#pragma unroll
    for (int fn = 0; fn < 2; ++fn) {
        nn[fn] = n0 + wn * 32 + fn * 16 + (lane & 15);
        okn[fn] = nn[fn] < NOPS;
        bev[fn] = okn[fn] ? be[nn[fn]] : 0.0f;
        osv[fn] = okn[fn] ? osq[nn[fn]] : 0.0f;
    }
#pragma unroll
    for (int fm = 0; fm < 4; ++fm) {
#pragma unroll
        for (int r = 0; r < 4; ++r) {
            int m = m0 + wm * 64 + fm * 16 + (lane >> 4) * 4 + r;
            float hs = hsq[m];
            u64 bestk = 0ull;
#pragma unroll
            for (int fn = 0; fn < 2; ++fn) {
                if (okn[fn]) {
                    float dot1 = acc1[fm][fn][r] + acc1x[fm][fn][r] * inv;
                    float dot2 = acc2[fm][fn][r] + acc2x[fm][fn][r] * inv;
                    float sc = (dot1 + bev[fn])
                             - 0.5f * sqrtf(fmaxf(hs + osv[fn] - 2.0f * dot2, 0.0f));
                    out[(size_t)m * NOPS + nn[fn]] = sc;
                    unsigned int u = __float_as_uint(sc);
                    unsigned int mono = (u & 0x80000000u) ? ~u : (u | 0x80000000u);
                    u64 key = ((u64)mono << 32) | (u64)(0xFFFFFFFFu - (unsigned)nn[fn]);
                    if (key > bestk) bestk = key;
                }
            }
#pragma unroll
            for (int off = 1; off < 16; off <<= 1) {
                u64 ok = __shfl_xor(bestk, off);
                if (ok > bestk) bestk = ok;
            }
            if ((lane & 15) == 0) atomicMax(amax + m, bestk);
        }
    }
}

// ---------------- final traj write for t = STEPS-1 ----------------
__global__ __launch_bounds__(256) void writetraj(const u64* __restrict__ amax,
                                                 float* __restrict__ traj) {
    int i = blockIdx.x * blockDim.x + threadIdx.x;
    if (i < B) {
        unsigned selv = 0xFFFFFFFFu - (unsigned)(amax[i] & 0xFFFFFFFFull);
        traj[i] = (float)selv;
    }
}

extern "C" void kernel_launch(void* const* d_in, const int* in_sizes, int n_in,
                              void* d_out, int out_size, void* d_ws, size_t ws_size,
                              hipStream_t stream) {
    const float* geo      = (const float*)d_in[0];
    const float* sem      = (const float*)d_in[1];
    const float* w_ih0    = (const float*)d_in[2];
    const float* w_hh0    = (const float*)d_in[3];
    const float* b_ih0    = (const float*)d_in[4];
    const float* b_hh0    = (const float*)d_in[5];
    const float* w_ih1    = (const float*)d_in[6];
    const float* w_hh1    = (const float*)d_in[7];
    const float* b_ih1    = (const float*)d_in[8];
    const float* b_hh1    = (const float*)d_in[9];
    const float* w_energy = (const float*)d_in[10];
    const float* b_energy = (const float*)d_in[11];
    const float* w_proj   = (const float*)d_in[12];
    const float* b_proj   = (const float*)d_in[13];
    const float* w_op     = (const float*)d_in[14];
    const float* op_emb   = (const float*)d_in[15];

    char* p = (char*)d_ws;
    auto alloc = [&](size_t bytes) { char* q = p; p += (bytes + 255) & ~255ULL; return q; };
    float* opp   = (float*)alloc((size_t)NOPS * 256 * 4);
    float* oppsq = (float*)alloc((size_t)NOPS * 4);
    float* hsq   = (float*)alloc((size_t)B * 4);
    u64*   amax  = (u64*)  alloc((size_t)B * 8);
    float* wcf   = (float*)alloc((size_t)768 * 512 * 4);
    float* bihc  = (float*)alloc((size_t)768 * 4);
    float *h0f[2], *h1f[2];
    f16 *h0c[2][3], *h1c[2][3];
    for (int i = 0; i < 2; ++i) {
        h0f[i] = (float*)alloc((size_t)B * H * 4);
        h1f[i] = (float*)alloc((size_t)B * H * 4);
        for (int j = 0; j < 3; ++j) {
            h0c[i][j] = (f16*)alloc((size_t)B * H * 2);
            h1c[i][j] = (f16*)alloc((size_t)B * H * 2);
        }
    }
    f16* x0 = (f16*)alloc((size_t)B * INDIM * 2);
    f16* x1 = (f16*)alloc((size_t)B * INDIM * 2);
    f16* x2 = (f16*)alloc((size_t)B * INDIM * 2);
    f16 *wi0[3], *wh0[3], *wi1[3], *wh1[3], *wc[3], *emb[3];
    for (int i = 0; i < 3; ++i) {
        wi0[i] = (f16*)alloc((size_t)768 * 320 * 2);
        wh0[i] = (f16*)alloc((size_t)768 * 256 * 2);
        wi1[i] = (f16*)alloc((size_t)768 * 256 * 2);
        wh1[i] = (f16*)alloc((size_t)768 * 256 * 2);
        wc[i]  = (f16*)alloc((size_t)768 * 512 * 2);
        emb[i] = (f16*)alloc((size_t)NOPS * 256 * 2);
    }
    f16* weh = (f16*)alloc((size_t)NOPS * 256 * 2);
    f16* wel = (f16*)alloc((size_t)NOPS * 256 * 2);
    f16* oph = (f16*)alloc((size_t)NOPS * 256 * 2);
    f16* opl = (f16*)alloc((size_t)NOPS * 256 * 2);

    float* out    = (float*)d_out;
    float* traj   = out;
    float* scores = out + (size_t)STEPS * B;

    init_kernel<<<dim3((B * INDIM + 255) / 256), dim3(256), 0, stream>>>(
        geo, sem, x0, x1, x2, h0f[0], h1f[0],
        h0c[0][0], h0c[0][1], h0c[0][2], h1c[0][0], h1c[0][1], h1c[0][2],
        hsq, amax);
    gemm_tn<<<dim3(256 / BN, (NOPS + BM - 1) / BM), dim3(256), 0, stream>>>(
        op_emb, w_op, nullptr, opp, NOPS, 256, 256);
    // Wc = Wi0 @ Wp (768x512); bihc = b_ih0 + Wi0 @ bp
    gemm_nn<<<dim3(512 / BN, 768 / BM), dim3(256), 0, stream>>>(w_ih0, w_proj, wcf, 768, 512, 320);
    rowdot_bias<<<dim3(192), dim3(256), 0, stream>>>(w_ih0, b_proj, b_ih0, bihc);
    cvt3_rows<<<dim3(192), dim3(256), 0, stream>>>(w_ih0, 768, 320, wi0[0], wi0[1], wi0[2]);
    cvt3_rows<<<dim3(192), dim3(256), 0, stream>>>(w_hh0, 768, 256, wh0[0], wh0[1], wh0[2]);
    cvt3_rows<<<dim3(192), dim3(256), 0, stream>>>(w_ih1, 768, 256, wi1[0], wi1[1], wi1[2]);
    cvt3_rows<<<dim3(192), dim3(256), 0, stream>>>(w_hh1, 768, 256, wh1[0], wh1[1], wh1[2]);
    cvt3_rows<<<dim3(192), dim3(256), 0, stream>>>(wcf, 768, 512, wc[0], wc[1], wc[2]);
    cvt3_rows<<<dim3((NOPS + 3) / 4), dim3(256), 0, stream>>>(op_emb, NOPS, 256, emb[0], emb[1], emb[2]);
    cvt_rows<<<dim3((NOPS + 3) / 4), dim3(256), 0, stream>>>(w_energy, NOPS, 256, weh, wel, nullptr);
    cvt_rows<<<dim3((NOPS + 3) / 4), dim3(256), 0, stream>>>(opp, NOPS, 256, oph, opl, oppsq);

    for (int t = 0; t < STEPS; ++t) {
        int pi = t & 1, po = pi ^ 1;

        if (t == 0) {
            gru_mfma3<<<dim3(H / 32, B / 64), dim3(512), 0, stream>>>(
                x0, x1, x2, INDIM, wi0[0], wi0[1], wi0[2],
                h0c[pi][0], h0c[pi][1], h0c[pi][2], wh0[0], wh0[1], wh0[2],
                b_ih0, b_hh0, h0f[pi], h0f[po], h0c[po][0], h0c[po][1], h0c[po][2],
                hsq, nullptr, nullptr);
        } else {
            // folded proj+gru0: A = [h1_prev, emb[sel_prev]] with Wc; writes traj[t-1]
            gru_mfma3_f<<<dim3(H / 32, B / 64), dim3(512), 0, stream>>>(
                h1c[pi][0], h1c[pi][1], h1c[pi][2],
                emb[0], emb[1], emb[2], amax,
                wc[0], wc[1], wc[2],
                h0c[pi][0], h0c[pi][1], h0c[pi][2], wh0[0], wh0[1], wh0[2],
                bihc, b_hh0, h0f[pi], h0f[po], h0c[po][0], h0c[po][1], h0c[po][2],
                hsq, traj + (size_t)(t - 1) * B);
        }
        // gru1: accumulates hsq, zeroes amax for this step's scores
        gru_mfma3<<<dim3(H / 32, B / 64), dim3(512), 0, stream>>>(
            h0c[po][0], h0c[po][1], h0c[po][2], 256, wi1[0], wi1[1], wi1[2],
            h1c[pi][0], h1c[pi][1], h1c[pi][2], wh1[0], wh1[1], wh1[2],
            b_ih1, b_hh1, h1f[pi], h1f[po], h1c[po][0], h1c[po][1], h1c[po][2],
            nullptr, hsq, amax);

        scores_mfma<<<dim3((NOPS + 63) / 64, B / 128), dim3(256), 0, stream>>>(
            h1c[po][0], h1c[po][1], weh, wel, oph, opl, hsq, b_energy, oppsq,
            scores + (size_t)t * B * NOPS, amax);
    }
    writetraj<<<dim3((B + 255) / 256), dim3(256), 0, stream>>>(amax, traj + (size_t)(STEPS - 1) * B);
}